// Round 10
// baseline (1744.425 us; speedup 1.0000x reference)
//
#include <hip/hip_runtime.h>
#include <math.h>
#include <float.h>

#define NB 8
#define NC 24
#define NA 96
#define NW 96
#define NF 32
#define NHID 128
#define AW (NA*NW)           // 9216
#define NBC (NB*NC)          // 192
#define NEL ((size_t)NBC*AW) // 1769472

// packed fp32: <2 x float> fma -> v_pk_fma_f32 on gfx90a+/gfx950
typedef float v2f __attribute__((ext_vector_type(2)));
typedef float f32x4 __attribute__((ext_vector_type(4)));
typedef short short8_t __attribute__((ext_vector_type(8)));
typedef unsigned int uint4v __attribute__((ext_vector_type(4)));
#ifndef __has_builtin
#define __has_builtin(x) 0
#endif
#if __has_builtin(__builtin_elementwise_fma)
#define PKFMA(a,b,c) __builtin_elementwise_fma((a),(b),(c))
#else
#define PKFMA(a,b,c) ((a)*(b)+(c))
#endif

union frag_u { unsigned int u[4]; uint4v v; short8_t s; };

__device__ __forceinline__ unsigned short bf16rne(float x) {
    unsigned int u = __float_as_uint(x);
    unsigned int r = u + 0x7fffu + ((u >> 16) & 1u);
    return (unsigned short)(r >> 16);
}

// ---------------------------------------------------------------- stats
__global__ __launch_bounds__(256) void stats_kernel(
    const float* __restrict__ x, const int* __restrict__ rows_len,
    const int* __restrict__ cols_len, float* __restrict__ stats)
{
    int bc = blockIdx.x;
    int R = rows_len[bc], L = cols_len[bc];
    const float* xp = x + (size_t)bc * AW;
    int n = R * L;
    float sx = 0.f, sxx = 0.f;
    for (int i = threadIdx.x; i < n; i += 256) {
        int a = i / L, w = i - a * L;
        float v = xp[a * NW + w];
        sx += v;
        sxx = fmaf(v, v, sxx);
    }
    __shared__ float r1[256], r2[256];
    r1[threadIdx.x] = sx; r2[threadIdx.x] = sxx;
    __syncthreads();
    for (int s = 128; s > 0; s >>= 1) {
        if (threadIdx.x < s) {
            r1[threadIdx.x] += r1[threadIdx.x + s];
            r2[threadIdx.x] += r2[threadIdx.x + s];
        }
        __syncthreads();
    }
    if (threadIdx.x == 0) {
        float fn = (float)n;
        float mean = r1[0] / fn;
        float var = fmaxf((r2[0] - r1[0] * r1[0] / fn) / (fn - 1.f), 0.f);
        float sd = fmaxf(sqrtf(var), 1e-12f);
        stats[2 * bc] = mean;
        stats[2 * bc + 1] = 1.f / sd;
    }
}

// ---------------------------------------------------------------- prep: transpose first 24 rows of each stack's W1
__global__ __launch_bounds__(256) void prep_kernel(
    const float* __restrict__ tw1, float* __restrict__ w1t)
{
    int i = blockIdx.x * 256 + threadIdx.x;     // [s][j][t]
    if (i >= 4 * NHID * 24) return;
    int s = i / (NHID * 24), r = i % (NHID * 24);
    int j = r / 24, t = r % 24;
    w1t[i] = tw1[(size_t)s * 64 * NHID + t * NHID + j];
}

// ---------------------------------------------------------------- prep2: split W2^T into bf16 hi/lo (per stack)
// tw2 layout [s][j=128][f=32] -> w2bf[s][hi=0/lo=1][f][j] ushort
__global__ __launch_bounds__(256) void prep2_kernel(
    const float* __restrict__ tw2, unsigned short* __restrict__ w2bf)
{
    int i = blockIdx.x * 256 + threadIdx.x;
    if (i >= 4 * NF * NHID) return;
    int s = i / (NF * NHID), r = i % (NF * NHID);
    int f = r / NHID, j = r % NHID;
    float v = tw2[((size_t)s * NHID + j) * NF + f];
    unsigned short hi = bf16rne(v);
    float hf = __uint_as_float(((unsigned int)hi) << 16);
    unsigned short lo = bf16rne(v - hf);
    size_t base = (size_t)s * (2 * NF * NHID) + (size_t)f * NHID + j;
    w2bf[base] = hi;
    w2bf[base + NF * NHID] = lo;
}

// ---------------------------------------------------------------- t0 MLP (1->128->32), packed-f accumulation
__global__ __launch_bounds__(256) void t0_kernel(
    const float* __restrict__ x, const int* __restrict__ rows_len,
    const int* __restrict__ cols_len, const float* __restrict__ stats,
    const float* __restrict__ w1, const float* __restrict__ b1,
    const float* __restrict__ w2, const float* __restrict__ b2,
    float* __restrict__ h)
{
    int tid = threadIdx.x;
    int bc = blockIdx.x / 18;
    int base = (blockIdx.x % 18) * 512;
    int R = rows_len[bc], L = cols_len[bc];
    float mean = stats[2 * bc], rstd = stats[2 * bc + 1];

    int eA = base + tid, eB = eA + 256;
    int aA = eA / NW, wA = eA % NW;
    int aB = eB / NW, wB = eB % NW;
    bool vA = (aA < R) && (wA < L);
    bool vB = (aB < R) && (wB < L);
    size_t gA = (size_t)bc * AW + eA;
    float xA = vA ? (x[gA] - mean) * rstd : 0.f;
    float xB = vB ? (x[gA + 256] - mean) * rstd : 0.f;

    v2f oA[16], oB[16];
    const v2f* b22 = (const v2f*)b2;
    #pragma unroll
    for (int i = 0; i < 16; i++) { v2f bb = b22[i]; oA[i] = bb; oB[i] = bb; }
    for (int j = 0; j < NHID; j++) {
        float hA = fmaxf(fmaf(xA, w1[j], b1[j]), 0.f);
        float hB = fmaxf(fmaf(xB, w1[j], b1[j]), 0.f);
        const v2f* wr = (const v2f*)&w2[j * NF];
        v2f hA2 = {hA, hA}, hB2 = {hB, hB};
        #pragma unroll
        for (int i = 0; i < 16; i++) {
            v2f q = wr[i];
            oA[i] = PKFMA(hA2, q, oA[i]);
            oB[i] = PKFMA(hB2, q, oB[i]);
        }
    }
    float mA = vA ? 1.f : 0.f, mB = vB ? 1.f : 0.f;
    float* hp = h + (size_t)bc * NF * AW;
    #pragma unroll
    for (int f = 0; f < NF; f++) {
        hp[(size_t)f * AW + eA] = oA[f >> 1][f & 1] * mA;
        hp[(size_t)f * AW + eB] = oB[f >> 1][f & 1] * mB;
    }
}

// ---------------------------------------------------------------- pools: one block per (bc, f) plane
__global__ __launch_bounds__(256) void pool_kernel(
    const float* __restrict__ h, float* __restrict__ rowsum,
    float* __restrict__ colsum, float* __restrict__ matsum,
    float* __restrict__ cmax)
{
    __shared__ float sred[4];
    __shared__ float scol[4][96];
    int blk = blockIdx.x;            // bc*32 + f
    int bc = blk >> 5, f = blk & 31;
    const float* p = h + (size_t)blk * AW;
    int tid = threadIdx.x;
    int lane = tid & 63, wv = tid >> 6;

    float mx = -FLT_MAX;
    for (int i = tid; i < AW; i += 256) mx = fmaxf(mx, p[i]);
    #pragma unroll
    for (int off = 32; off >= 1; off >>= 1) mx = fmaxf(mx, __shfl_xor(mx, off, 64));
    if (lane == 0) sred[wv] = mx;
    __syncthreads();
    if (tid == 0)
        cmax[bc * NF + f] = fmaxf(fmaxf(sred[0], sred[1]), fmaxf(sred[2], sred[3]));

    int mode = f & 3, k = f >> 2;
    if (mode == 1) {
        for (int r = 0; r < 24; r++) {
            int a = wv + 4 * r;
            float v1 = p[a * NW + lane];
            float s = __sinf(v1);
            if (lane < 32) s += __sinf(p[a * NW + 64 + lane]);
            #pragma unroll
            for (int off = 32; off >= 1; off >>= 1) s += __shfl_xor(s, off, 64);
            if (lane == 0) rowsum[(bc * NA + a) * 8 + k] = s;
        }
    } else if (mode == 2) {
        float acc0 = 0.f, acc1 = 0.f;
        for (int r = 0; r < 24; r++) {
            int a = wv + 4 * r;
            acc0 += __sinf(p[a * NW + lane]);
            if (lane < 32) acc1 += __sinf(p[a * NW + 64 + lane]);
        }
        scol[wv][lane] = acc0;
        if (lane < 32) scol[wv][64 + lane] = acc1;
        __syncthreads();
        if (tid < 96)
            colsum[(bc * NW + tid) * 8 + k] =
                scol[0][tid] + scol[1][tid] + scol[2][tid] + scol[3][tid];
    } else if (mode == 3) {
        float s = 0.f;
        for (int i = tid; i < AW; i += 256) s += __sinf(p[i]);
        #pragma unroll
        for (int off = 32; off >= 1; off >>= 1) s += __shfl_xor(s, off, 64);
        __syncthreads();
        if (lane == 0) sred[wv] = s;
        __syncthreads();
        if (tid == 0) matsum[bc * 8 + k] = sred[0] + sred[1] + sred[2] + sred[3];
    }
}

// ---------------------------------------------------------------- precompute per-(bc): rowc[j][a], colc[j][w]
__global__ __launch_bounds__(256) void precomp_kernel(
    const float* __restrict__ rowsum, const float* __restrict__ colsum,
    const float* __restrict__ matsum, const float* __restrict__ cmax,
    const float* __restrict__ w1, const float* __restrict__ b1,
    float* __restrict__ rowc, float* __restrict__ colc)
{
    __shared__ float sbm[NF];
    __shared__ float sconst[NHID];
    int tid = threadIdx.x;
    int bc = blockIdx.x, b = bc / NC;
    if (tid < NF) {
        float m = cmax[(b * NC) * NF + tid];
        for (int c = 1; c < NC; c++) m = fmaxf(m, cmax[(b * NC + c) * NF + tid]);
        sbm[tid] = m;
    }
    __syncthreads();
    if (tid < NHID) {
        float v = b1[tid];
        const float* mp = matsum + bc * 8;
        #pragma unroll
        for (int k = 0; k < 8; k++) v = fmaf(mp[k], w1[(24 + k) * NHID + tid], v);
        #pragma unroll
        for (int f = 0; f < NF; f++) v = fmaf(sbm[f], w1[(32 + f) * NHID + tid], v);
        sconst[tid] = v;
    }
    __syncthreads();
    for (int i = tid; i < NHID * NA; i += 256) {
        int j = i / NA, aa = i - j * NA;
        const float* rp = rowsum + (bc * NA + aa) * 8;
        float v = sconst[j];
        #pragma unroll
        for (int k = 0; k < 8; k++) v = fmaf(rp[k], w1[(8 + k) * NHID + j], v);
        rowc[(size_t)bc * (NHID * NA) + i] = v;
    }
    for (int i = tid; i < NHID * NW; i += 256) {
        int j = i / NW, ww = i - j * NW;
        const float* cp = colsum + (bc * NW + ww) * 8;
        float v = 0.f;
        #pragma unroll
        for (int k = 0; k < 8; k++) v = fmaf(cp[k], w1[(16 + k) * NHID + j], v);
        colc[(size_t)bc * (NHID * NW) + i] = v;
    }
}

// ---------------------------------------------------------------- stack MLP v11: chunk-XOR-swizzled LDS
// r9 lesson: HSTR=17 did NOT fix conflicts (identical 7.08M count as v8) —
// phase-B banks (17*c16+4g)%32 peak at 4 lanes/bank, and 4B alignment split
// every b128 into 4 b32s. v11: HSTR=16 (16B-aligned, true b128 both ways) +
// XOR of the 16B-chunk index with (e>>1)&3. Both write (fixed q) and read
// (fixed g) patterns then land exactly 8 lanes per 4-bank group = bandwidth
// minimum, zero conflicts. LDS 34.8->32.0 KB -> 5 blocks/CU (sq_lds aliases
// dead hid_hi). Math bit-identical to v10.
__global__ __launch_bounds__(256, 5) void mlp_kernel(
    float* __restrict__ h, const float* __restrict__ rowc,
    const float* __restrict__ colc, const int* __restrict__ rows_len,
    const int* __restrict__ cols_len, const float* __restrict__ w1t,
    const unsigned short* __restrict__ w2bf, const float* __restrict__ b2,
    float* __restrict__ sqsum, int last)
{
    __shared__ __align__(16) unsigned int hid_hi[256 * 16];  // 16 KB
    __shared__ __align__(16) unsigned int hid_lo[256 * 16];  // 16 KB (32 KB total)

    int tid = threadIdx.x;
    int bc = blockIdx.x / 36;
    int base = (blockIdx.x % 36) * 256;
    int lane = tid & 63, wv = tid >> 6;
    int g = lane >> 4, c16 = lane & 15;
    int wsw = (tid >> 1) & 3;           // write-side chunk swizzle (own row e=tid)
    int rsw = (c16 >> 1) & 3;           // read-side: (el>>1)&3 == (c16>>1)&3

    // phase-A element for this thread
    int e = base + tid;
    int a = e / NW, wc = e - a * NW;
    float* hp = h + (size_t)bc * NF * AW;

    // sin of the 8 e0 channels (planes 4k), hoisted across windows
    float p[8];
    #pragma unroll
    for (int k = 0; k < 8; k++) p[k] = __sinf(hp[(size_t)(4 * k) * AW + e]);
    v2f p2[4];
    #pragma unroll
    for (int t = 0; t < 4; t++) p2[t] = (v2f){p[2 * t], p[2 * t + 1]};

    const unsigned short* w2hi = w2bf;
    const unsigned short* w2lo = w2bf + NF * NHID;

    // accumulators: [e-tile][f-tile], init = b2 (reg r <-> f = 4g+r+16t)
    f32x4 acc[4][2];
    #pragma unroll
    for (int t = 0; t < 2; t++) {
        f32x4 bb = *(const f32x4*)(b2 + 16 * t + 4 * g);
        #pragma unroll
        for (int ti = 0; ti < 4; ti++) acc[ti][t] = bb;
    }

    const float* rcr = rowc + (size_t)bc * (NHID * NA);
    const float* rcc = colc + (size_t)bc * (NHID * NW);

    for (int w = 0; w < 4; w++) {
        int jw = 32 * w;
        // ---- A-fragments for this window (global, L2-broadcast; used in phase B)
        frag_u Ah[2], Al[2];
        #pragma unroll
        for (int t = 0; t < 2; t++) {
            size_t off = (size_t)(c16 + 16 * t) * NHID + jw + 8 * g;  // 16B-aligned
            const unsigned int* ph = (const unsigned int*)(w2hi + off);
            const unsigned int* pl = (const unsigned int*)(w2lo + off);
            #pragma unroll
            for (int d = 0; d < 4; d++) { Ah[t].u[d] = ph[d]; Al[t].u[d] = pl[d]; }
        }

        // ---- phase A: hidden fp32 -> bf16 hi/lo -> LDS (b128 per 4-jp chunk)
        #pragma unroll
        for (int q = 0; q < 4; q++) {
            unsigned int hi4[4], lo4[4];
            #pragma unroll
            for (int d = 0; d < 4; d++) {
                int jl = 2 * (4 * q + d);
                const v2f* w1r0 = (const v2f*)(w1t + (size_t)(jw + jl) * 24);
                const v2f* w1r1 = w1r0 + 12;
                v2f u0 = {rcr[(size_t)(jw + jl) * NA + a], rcc[(size_t)(jw + jl) * NW + wc]};
                v2f u1 = {rcr[(size_t)(jw + jl + 1) * NA + a], rcc[(size_t)(jw + jl + 1) * NW + wc]};
                #pragma unroll
                for (int t = 0; t < 4; t++) {
                    u0 = PKFMA(p2[t], w1r0[t], u0);
                    u1 = PKFMA(p2[t], w1r1[t], u1);
                }
                float v0 = fmaxf(u0.x + u0.y, 0.f);
                float v1 = fmaxf(u1.x + u1.y, 0.f);
                unsigned int hi, lo;
                asm("v_cvt_pk_bf16_f32 %0, %1, %2" : "=v"(hi) : "v"(v0), "v"(v1));
                float h0 = __uint_as_float(hi << 16);
                float h1 = __uint_as_float(hi & 0xffff0000u);
                float l0 = v0 - h0, l1 = v1 - h1;
                asm("v_cvt_pk_bf16_f32 %0, %1, %2" : "=v"(lo) : "v"(l0), "v"(l1));
                hi4[d] = hi; lo4[d] = lo;
            }
            int dst = tid * 16 + 4 * (q ^ wsw);
            *(uint4v*)&hid_hi[dst] = (uint4v){hi4[0], hi4[1], hi4[2], hi4[3]};
            *(uint4v*)&hid_lo[dst] = (uint4v){lo4[0], lo4[1], lo4[2], lo4[3]};
        }
        __syncthreads();   // hidden visible

        // ---- phase B: MFMA over this K-window; wave wv owns e-tiles 4wv..4wv+3
        #pragma unroll
        for (int ti = 0; ti < 4; ti++) {
            int el = (wv * 4 + ti) * 16 + c16;
            int src = el * 16 + 4 * (g ^ rsw);
            frag_u Bh, Bl;
            Bh.v = *(const uint4v*)&hid_hi[src];
            Bl.v = *(const uint4v*)&hid_lo[src];
            #pragma unroll
            for (int t = 0; t < 2; t++) {
                acc[ti][t] = __builtin_amdgcn_mfma_f32_16x16x32_bf16(Ah[t].s, Bh.s, acc[ti][t], 0, 0, 0);
                acc[ti][t] = __builtin_amdgcn_mfma_f32_16x16x32_bf16(Al[t].s, Bh.s, acc[ti][t], 0, 0, 0);
                acc[ti][t] = __builtin_amdgcn_mfma_f32_16x16x32_bf16(Ah[t].s, Bl.s, acc[ti][t], 0, 0, 0);
            }
        }
        __syncthreads();   // hid consumed; next window may overwrite
    }

    // ---- epilogue: residual RMW + mask; lane covers e = base+el, f = 4g+r+16t
    int R = rows_len[bc], L = cols_len[bc];
    float psum[2][4] = {{0.f, 0.f, 0.f, 0.f}, {0.f, 0.f, 0.f, 0.f}};
    #pragma unroll
    for (int ti = 0; ti < 4; ti++) {
        int el = (wv * 4 + ti) * 16 + c16;
        int ee = base + el;
        int aa = ee / NW, ww = ee - aa * NW;
        float mk = (aa < R && ww < L) ? 1.f : 0.f;
        #pragma unroll
        for (int t = 0; t < 2; t++) {
            #pragma unroll
            for (int r = 0; r < 4; r++) {
                int f = 4 * g + r + 16 * t;
                float* ad = hp + (size_t)f * AW + ee;
                float hv = (*ad + acc[ti][t][r]) * mk;
                if (!last) *ad = hv;
                else       psum[t][r] = fmaf(hv, hv, psum[t][r]);
            }
        }
    }
    if (last) {
        float* sq_lds = (float*)hid_hi;   // hid is dead after last phase-B barrier
        if (tid < NF) sq_lds[tid] = 0.f;
        __syncthreads();
        #pragma unroll
        for (int t = 0; t < 2; t++) {
            #pragma unroll
            for (int r = 0; r < 4; r++) {
                float v = psum[t][r];
                v += __shfl_xor(v, 1, 64);
                v += __shfl_xor(v, 2, 64);
                v += __shfl_xor(v, 4, 64);
                v += __shfl_xor(v, 8, 64);   // masks <16: stays within c16 group
                if (c16 == 0) atomicAdd(&sq_lds[4 * g + r + 16 * t], v);
            }
        }
        __syncthreads();
        if (tid < NF) atomicAdd(&sqsum[bc * NF + tid], sq_lds[tid]);
    }
}

// ---------------------------------------------------------------- final: rms from sqsum + mean-over-C + MLP + tanh
__global__ __launch_bounds__(64) void out_kernel(
    const float* __restrict__ sqsum, const int* __restrict__ rows_len,
    const int* __restrict__ cols_len, const float* __restrict__ w1,
    const float* __restrict__ b1, const float* __restrict__ w2,
    const float* __restrict__ b2, float* __restrict__ out)
{
    int b = threadIdx.x;
    if (b >= NB) return;
    float hm[NF];
    #pragma unroll
    for (int f = 0; f < NF; f++) hm[f] = 0.f;
    for (int c = 0; c < NC; c++) {
        int bc = b * NC + c;
        float n = (float)(rows_len[bc] * cols_len[bc]);
        float rdn = 1.f / fmaxf(n, 1e-12f);
        #pragma unroll
        for (int f = 0; f < NF; f++) {
            float q = fmaxf(sqsum[bc * NF + f], 1e-20f);
            hm[f] += sqrtf(q * rdn);
        }
    }
    #pragma unroll
    for (int f = 0; f < NF; f++) hm[f] *= (1.f / (float)NC);

    float o0 = b2[0], o1 = b2[1];
    for (int j = 0; j < NHID; j++) {
        float v = b1[j];
        #pragma unroll
        for (int f = 0; f < NF; f++) v = fmaf(hm[f], w1[f * NHID + j], v);
        v = fmaxf(v, 0.f);
        o0 = fmaf(v, w2[j * 2 + 0], o0);
        o1 = fmaf(v, w2[j * 2 + 1], o1);
    }
    out[b * 2 + 0] = 8.f * tanhf(o0);
    out[b * 2 + 1] = 8.f * tanhf(o1);
}

// ---------------------------------------------------------------- launcher
extern "C" void kernel_launch(void* const* d_in, const int* in_sizes, int n_in,
                              void* d_out, int out_size, void* d_ws, size_t ws_size,
                              hipStream_t stream)
{
    const float* x    = (const float*)d_in[0];
    const int* rl     = (const int*)d_in[1];
    const int* cl     = (const int*)d_in[2];
    const float* t0w1 = (const float*)d_in[3];
    const float* t0b1 = (const float*)d_in[4];
    const float* t0w2 = (const float*)d_in[5];
    const float* t0b2 = (const float*)d_in[6];
    const float* tw1  = (const float*)d_in[7];
    const float* tb1  = (const float*)d_in[8];
    const float* tw2  = (const float*)d_in[9];
    const float* tb2  = (const float*)d_in[10];
    const float* ow1  = (const float*)d_in[11];
    const float* ob1  = (const float*)d_in[12];
    const float* ow2  = (const float*)d_in[13];
    const float* ob2  = (const float*)d_in[14];
    float* out = (float*)d_out;

    float* ws    = (float*)d_ws;
    float* h     = ws;                               // NEL*NF  (planar [bc][f][a*96+w])
    float* stats = h + NEL * NF;                     // 2*NBC
    float* rowb  = stats + 2 * NBC;                  // NBC*NA*8
    float* colb  = rowb + (size_t)NBC * NA * 8;      // NBC*NW*8
    float* matb  = colb + (size_t)NBC * NW * 8;      // NBC*8
    float* cmxb  = matb + NBC * 8;                   // NBC*NF
    float* sqb   = cmxb + NBC * NF;                  // NBC*NF (sum of h^2)
    float* w1tb  = sqb + NBC * NF;                   // 4*NHID*24
    float* rowcb = w1tb + 4 * NHID * 24;             // NBC*NHID*NA
    float* colcb = rowcb + (size_t)NBC * NHID * NA;  // NBC*NHID*NW
    unsigned short* w2bfb = (unsigned short*)(colcb + (size_t)NBC * NHID * NW); // 4*2*NF*NHID ushort

    hipMemsetAsync(sqb, 0, NBC * NF * sizeof(float), stream);
    stats_kernel<<<NBC, 256, 0, stream>>>(x, rl, cl, stats);
    prep_kernel<<<(4 * NHID * 24 + 255) / 256, 256, 0, stream>>>(tw1, w1tb);
    prep2_kernel<<<(4 * NF * NHID + 255) / 256, 256, 0, stream>>>(tw2, w2bfb);
    t0_kernel<<<(int)(NEL / 512), 256, 0, stream>>>(x, rl, cl, stats,
                                                    t0w1, t0b1, t0w2, t0b2, h);
    for (int s = 0; s < 4; s++) {
        pool_kernel<<<NBC * NF, 256, 0, stream>>>(h, rowb, colb, matb, cmxb);
        precomp_kernel<<<NBC, 256, 0, stream>>>(rowb, colb, matb, cmxb,
            tw1 + (size_t)s * 64 * NHID, tb1 + s * NHID, rowcb, colcb);
        mlp_kernel<<<NBC * 36, 256, 0, stream>>>(h, rowcb, colcb, rl, cl,
            w1tb + (size_t)s * NHID * 24,
            w2bfb + (size_t)s * (2 * NF * NHID),
            tb2 + s * NF, sqb, (s == 3) ? 1 : 0);
    }
    out_kernel<<<1, 64, 0, stream>>>(sqb, rl, cl, ow1, ob1, ow2, ob2, out);
}

// Round 11
// 1585.244 us; speedup vs baseline: 1.1004x; 1.1004x over previous
//
#include <hip/hip_runtime.h>
#include <math.h>
#include <float.h>

#define NB 8
#define NC 24
#define NA 96
#define NW 96
#define NF 32
#define NHID 128
#define AW (NA*NW)           // 9216
#define NBC (NB*NC)          // 192
#define NEL ((size_t)NBC*AW) // 1769472
#define HSTR 17              // hid LDS row stride in dwords (v10-proven: 210us)

// packed fp32: <2 x float> fma -> v_pk_fma_f32 on gfx90a+/gfx950
typedef float v2f __attribute__((ext_vector_type(2)));
typedef float f32x4 __attribute__((ext_vector_type(4)));
typedef short short8_t __attribute__((ext_vector_type(8)));
#ifndef __has_builtin
#define __has_builtin(x) 0
#endif
#if __has_builtin(__builtin_elementwise_fma)
#define PKFMA(a,b,c) __builtin_elementwise_fma((a),(b),(c))
#else
#define PKFMA(a,b,c) ((a)*(b)+(c))
#endif

union frag_u { unsigned int u[4]; short8_t s; };

__device__ __forceinline__ unsigned short bf16rne(float x) {
    unsigned int u = __float_as_uint(x);
    unsigned int r = u + 0x7fffu + ((u >> 16) & 1u);
    return (unsigned short)(r >> 16);
}
// monotone float<->uint key (handles negatives); key(x1)<key(x2) iff x1<x2
__device__ __forceinline__ unsigned fkey(float x) {
    unsigned u = __float_as_uint(x);
    return (u >> 31) ? ~u : (u | 0x80000000u);
}
__device__ __forceinline__ float funkey(unsigned k) {
    return (k >> 31) ? __uint_as_float(k ^ 0x80000000u) : __uint_as_float(~k);
}

// ---------------------------------------------------------------- stats
__global__ __launch_bounds__(256) void stats_kernel(
    const float* __restrict__ x, const int* __restrict__ rows_len,
    const int* __restrict__ cols_len, float* __restrict__ stats)
{
    int bc = blockIdx.x;
    int R = rows_len[bc], L = cols_len[bc];
    const float* xp = x + (size_t)bc * AW;
    int n = R * L;
    float sx = 0.f, sxx = 0.f;
    for (int i = threadIdx.x; i < n; i += 256) {
        int a = i / L, w = i - a * L;
        float v = xp[a * NW + w];
        sx += v;
        sxx = fmaf(v, v, sxx);
    }
    __shared__ float r1[256], r2[256];
    r1[threadIdx.x] = sx; r2[threadIdx.x] = sxx;
    __syncthreads();
    for (int s = 128; s > 0; s >>= 1) {
        if (threadIdx.x < s) {
            r1[threadIdx.x] += r1[threadIdx.x + s];
            r2[threadIdx.x] += r2[threadIdx.x + s];
        }
        __syncthreads();
    }
    if (threadIdx.x == 0) {
        float fn = (float)n;
        float mean = r1[0] / fn;
        float var = fmaxf((r2[0] - r1[0] * r1[0] / fn) / (fn - 1.f), 0.f);
        float sd = fmaxf(sqrtf(var), 1e-12f);
        stats[2 * bc] = mean;
        stats[2 * bc + 1] = 1.f / sd;
    }
}

// ---------------------------------------------------------------- prep: transpose first 24 rows of each stack's W1
__global__ __launch_bounds__(256) void prep_kernel(
    const float* __restrict__ tw1, float* __restrict__ w1t)
{
    int i = blockIdx.x * 256 + threadIdx.x;     // [s][j][t]
    if (i >= 4 * NHID * 24) return;
    int s = i / (NHID * 24), r = i % (NHID * 24);
    int j = r / 24, t = r % 24;
    w1t[i] = tw1[(size_t)s * 64 * NHID + t * NHID + j];
}

// ---------------------------------------------------------------- prep2: split W2^T into bf16 hi/lo (per stack)
__global__ __launch_bounds__(256) void prep2_kernel(
    const float* __restrict__ tw2, unsigned short* __restrict__ w2bf)
{
    int i = blockIdx.x * 256 + threadIdx.x;
    if (i >= 4 * NF * NHID) return;
    int s = i / (NF * NHID), r = i % (NF * NHID);
    int f = r / NHID, j = r % NHID;
    float v = tw2[((size_t)s * NHID + j) * NF + f];
    unsigned short hi = bf16rne(v);
    float hf = __uint_as_float(((unsigned int)hi) << 16);
    unsigned short lo = bf16rne(v - hf);
    size_t base = (size_t)s * (2 * NF * NHID) + (size_t)f * NHID + j;
    w2bf[base] = hi;
    w2bf[base + NF * NHID] = lo;
}

// ---------------------------------------------------------------- t0 MLP (1->128->32), packed-f accumulation
__global__ __launch_bounds__(256) void t0_kernel(
    const float* __restrict__ x, const int* __restrict__ rows_len,
    const int* __restrict__ cols_len, const float* __restrict__ stats,
    const float* __restrict__ w1, const float* __restrict__ b1,
    const float* __restrict__ w2, const float* __restrict__ b2,
    float* __restrict__ h)
{
    int tid = threadIdx.x;
    int bc = blockIdx.x / 18;
    int base = (blockIdx.x % 18) * 512;
    int R = rows_len[bc], L = cols_len[bc];
    float mean = stats[2 * bc], rstd = stats[2 * bc + 1];

    int eA = base + tid, eB = eA + 256;
    int aA = eA / NW, wA = eA % NW;
    int aB = eB / NW, wB = eB % NW;
    bool vA = (aA < R) && (wA < L);
    bool vB = (aB < R) && (wB < L);
    size_t gA = (size_t)bc * AW + eA;
    float xA = vA ? (x[gA] - mean) * rstd : 0.f;
    float xB = vB ? (x[gA + 256] - mean) * rstd : 0.f;

    v2f oA[16], oB[16];
    const v2f* b22 = (const v2f*)b2;
    #pragma unroll
    for (int i = 0; i < 16; i++) { v2f bb = b22[i]; oA[i] = bb; oB[i] = bb; }
    for (int j = 0; j < NHID; j++) {
        float hA = fmaxf(fmaf(xA, w1[j], b1[j]), 0.f);
        float hB = fmaxf(fmaf(xB, w1[j], b1[j]), 0.f);
        const v2f* wr = (const v2f*)&w2[j * NF];
        v2f hA2 = {hA, hA}, hB2 = {hB, hB};
        #pragma unroll
        for (int i = 0; i < 16; i++) {
            v2f q = wr[i];
            oA[i] = PKFMA(hA2, q, oA[i]);
            oB[i] = PKFMA(hB2, q, oB[i]);
        }
    }
    float mA = vA ? 1.f : 0.f, mB = vB ? 1.f : 0.f;
    float* hp = h + (size_t)bc * NF * AW;
    #pragma unroll
    for (int f = 0; f < NF; f++) {
        hp[(size_t)f * AW + eA] = oA[f >> 1][f & 1] * mA;
        hp[(size_t)f * AW + eB] = oB[f >> 1][f & 1] * mB;
    }
}

// ---------------------------------------------------------------- pool (only for stack 0, after t0)
__global__ __launch_bounds__(256) void pool_kernel(
    const float* __restrict__ h, float* __restrict__ rowsum,
    float* __restrict__ colsum, float* __restrict__ matsum,
    unsigned* __restrict__ cmax_key)
{
    __shared__ float sred[4];
    __shared__ float scol[4][96];
    int blk = blockIdx.x;            // bc*32 + f
    int bc = blk >> 5, f = blk & 31;
    const float* p = h + (size_t)blk * AW;
    int tid = threadIdx.x;
    int lane = tid & 63, wv = tid >> 6;

    float mx = -FLT_MAX;
    for (int i = tid; i < AW; i += 256) mx = fmaxf(mx, p[i]);
    #pragma unroll
    for (int off = 32; off >= 1; off >>= 1) mx = fmaxf(mx, __shfl_xor(mx, off, 64));
    if (lane == 0) sred[wv] = mx;
    __syncthreads();
    if (tid == 0)
        cmax_key[bc * NF + f] =
            fkey(fmaxf(fmaxf(sred[0], sred[1]), fmaxf(sred[2], sred[3])));

    int mode = f & 3, k = f >> 2;
    if (mode == 1) {
        for (int r = 0; r < 24; r++) {
            int a = wv + 4 * r;
            float v1 = p[a * NW + lane];
            float s = __sinf(v1);
            if (lane < 32) s += __sinf(p[a * NW + 64 + lane]);
            #pragma unroll
            for (int off = 32; off >= 1; off >>= 1) s += __shfl_xor(s, off, 64);
            if (lane == 0) rowsum[(bc * NA + a) * 8 + k] = s;
        }
    } else if (mode == 2) {
        float acc0 = 0.f, acc1 = 0.f;
        for (int r = 0; r < 24; r++) {
            int a = wv + 4 * r;
            acc0 += __sinf(p[a * NW + lane]);
            if (lane < 32) acc1 += __sinf(p[a * NW + 64 + lane]);
        }
        scol[wv][lane] = acc0;
        if (lane < 32) scol[wv][64 + lane] = acc1;
        __syncthreads();
        if (tid < 96)
            colsum[(bc * NW + tid) * 8 + k] =
                scol[0][tid] + scol[1][tid] + scol[2][tid] + scol[3][tid];
    } else if (mode == 3) {
        float s = 0.f;
        for (int i = tid; i < AW; i += 256) s += __sinf(p[i]);
        #pragma unroll
        for (int off = 32; off >= 1; off >>= 1) s += __shfl_xor(s, off, 64);
        __syncthreads();
        if (lane == 0) sred[wv] = s;
        __syncthreads();
        if (tid == 0) matsum[bc * 8 + k] = sred[0] + sred[1] + sred[2] + sred[3];
    }
}

// ---------------------------------------------------------------- precompute per-(bc): rowc[j][a], colc[j][w]
// npart==0: colsum read direct (pool_kernel). npart==36: reduce per-block
// partials written by mlp's fused pool epilogue.
__global__ __launch_bounds__(256) void precomp_kernel(
    const float* __restrict__ rowsum, const float* __restrict__ colsum,
    const float* __restrict__ colpart, const float* __restrict__ matsum,
    const unsigned* __restrict__ cmax_key, const float* __restrict__ w1,
    const float* __restrict__ b1, float* __restrict__ rowc,
    float* __restrict__ colc, int npart)
{
    __shared__ float sbm[NF];
    __shared__ float sconst[NHID];
    __shared__ float scs[NW * 8];
    int tid = threadIdx.x;
    int bc = blockIdx.x, b = bc / NC;

    if (npart == 0) {
        for (int i = tid; i < NW * 8; i += 256) scs[i] = colsum[bc * NW * 8 + i];
    } else {
        for (int i = tid; i < NW * 8; i += 256) {
            float acc = 0.f;
            const float* cp = colpart + (size_t)bc * npart * (NW * 8) + i;
            for (int p = 0; p < npart; p++) acc += cp[(size_t)p * (NW * 8)];
            scs[i] = acc;
        }
    }
    if (tid < NF) {
        unsigned km = cmax_key[(b * NC) * NF + tid];
        for (int c = 1; c < NC; c++) {
            unsigned kc = cmax_key[(b * NC + c) * NF + tid];
            km = (kc > km) ? kc : km;
        }
        sbm[tid] = funkey(km);
    }
    __syncthreads();
    if (tid < NHID) {
        float v = b1[tid];
        const float* mp = matsum + bc * 8;
        #pragma unroll
        for (int k = 0; k < 8; k++) v = fmaf(mp[k], w1[(24 + k) * NHID + tid], v);
        #pragma unroll
        for (int f = 0; f < NF; f++) v = fmaf(sbm[f], w1[(32 + f) * NHID + tid], v);
        sconst[tid] = v;
    }
    __syncthreads();
    for (int i = tid; i < NHID * NA; i += 256) {
        int j = i / NA, aa = i - j * NA;
        const float* rp = rowsum + (bc * NA + aa) * 8;
        float v = sconst[j];
        #pragma unroll
        for (int k = 0; k < 8; k++) v = fmaf(rp[k], w1[(8 + k) * NHID + j], v);
        rowc[(size_t)bc * (NHID * NA) + i] = v;
    }
    for (int i = tid; i < NHID * NW; i += 256) {
        int j = i / NW, ww = i - j * NW;
        float v = 0.f;
        #pragma unroll
        for (int k = 0; k < 8; k++) v = fmaf(scs[ww * 8 + k], w1[(16 + k) * NHID + j], v);
        colc[(size_t)bc * (NHID * NW) + i] = v;
    }
}

// ---------------------------------------------------------------- stack MLP v12: v10 core + fused pool epilogue
// Core identical to v10 (210us measured): HSTR=17, (256,4), unroll-4 phase A.
// do_pool (s<3): epilogue computes next stack's pools from the in-register hv:
//   r=1 -> rowsum (shfl c16-reduce -> LDS -> 24-32 global atomicAdd/block)
//   r=2 -> colsum (LDS [96][8] atomics -> per-block PARTIAL write, no global atomics)
//   r=3 -> matsum (register accum -> shfl -> LDS -> 8 atomics)
//   all -> cmax   (register max -> shfl -> LDS atomicMax on uint keys -> 32 global)
// last (s==3): sqsum path (v10), pools skipped, h not written.
__global__ __launch_bounds__(256, 4) void mlp_kernel(
    float* __restrict__ h, const float* __restrict__ rowc,
    const float* __restrict__ colc, const int* __restrict__ rows_len,
    const int* __restrict__ cols_len, const float* __restrict__ w1t,
    const unsigned short* __restrict__ w2bf, const float* __restrict__ b2,
    float* __restrict__ sqsum, float* __restrict__ rowsum,
    float* __restrict__ colpart, float* __restrict__ matsum,
    unsigned* __restrict__ cmax_key, int last, int do_pool)
{
    __shared__ unsigned int hid_hi[256 * HSTR];  // 17.4 KB
    __shared__ unsigned int hid_lo[256 * HSTR];  // 17.4 KB

    int tid = threadIdx.x;
    int bc = blockIdx.x / 36;
    int blk36 = blockIdx.x % 36;
    int base = blk36 * 256;
    int lane = tid & 63, wv = tid >> 6;
    int g = lane >> 4, c16 = lane & 15;

    int e = base + tid;
    int a = e / NW, wc = e - a * NW;
    float* hp = h + (size_t)bc * NF * AW;

    float p[8];
    #pragma unroll
    for (int k = 0; k < 8; k++) p[k] = __sinf(hp[(size_t)(4 * k) * AW + e]);
    v2f p2[4];
    #pragma unroll
    for (int t = 0; t < 4; t++) p2[t] = (v2f){p[2 * t], p[2 * t + 1]};

    const unsigned short* w2hi = w2bf;
    const unsigned short* w2lo = w2bf + NF * NHID;

    f32x4 acc[4][2];
    #pragma unroll
    for (int t = 0; t < 2; t++) {
        f32x4 bb = *(const f32x4*)(b2 + 16 * t + 4 * g);
        #pragma unroll
        for (int ti = 0; ti < 4; ti++) acc[ti][t] = bb;
    }

    const float* rcr = rowc + (size_t)bc * (NHID * NA);
    const float* rcc = colc + (size_t)bc * (NHID * NW);

    for (int w = 0; w < 4; w++) {
        int jw = 32 * w;
        frag_u Ah[2], Al[2];
        #pragma unroll
        for (int t = 0; t < 2; t++) {
            size_t off = (size_t)(c16 + 16 * t) * NHID + jw + 8 * g;
            const unsigned int* ph = (const unsigned int*)(w2hi + off);
            const unsigned int* pl = (const unsigned int*)(w2lo + off);
            #pragma unroll
            for (int d = 0; d < 4; d++) { Ah[t].u[d] = ph[d]; Al[t].u[d] = pl[d]; }
        }

        #pragma unroll 4
        for (int jp = 0; jp < 16; jp++) {
            int jl = 2 * jp;
            const v2f* w1r0 = (const v2f*)(w1t + (size_t)(jw + jl) * 24);
            const v2f* w1r1 = w1r0 + 12;
            v2f u0 = {rcr[(size_t)(jw + jl) * NA + a], rcc[(size_t)(jw + jl) * NW + wc]};
            v2f u1 = {rcr[(size_t)(jw + jl + 1) * NA + a], rcc[(size_t)(jw + jl + 1) * NW + wc]};
            #pragma unroll
            for (int t = 0; t < 4; t++) {
                u0 = PKFMA(p2[t], w1r0[t], u0);
                u1 = PKFMA(p2[t], w1r1[t], u1);
            }
            float v0 = fmaxf(u0.x + u0.y, 0.f);
            float v1 = fmaxf(u1.x + u1.y, 0.f);
            unsigned int hi, lo;
            asm("v_cvt_pk_bf16_f32 %0, %1, %2" : "=v"(hi) : "v"(v0), "v"(v1));
            float h0 = __uint_as_float(hi << 16);
            float h1 = __uint_as_float(hi & 0xffff0000u);
            float l0 = v0 - h0, l1 = v1 - h1;
            asm("v_cvt_pk_bf16_f32 %0, %1, %2" : "=v"(lo) : "v"(l0), "v"(l1));
            hid_hi[tid * HSTR + jp] = hi;
            hid_lo[tid * HSTR + jp] = lo;
        }
        __syncthreads();

        #pragma unroll
        for (int ti = 0; ti < 4; ti++) {
            int el = (wv * 4 + ti) * 16 + c16;
            const unsigned int* bh = &hid_hi[el * HSTR + 4 * g];
            const unsigned int* bl = &hid_lo[el * HSTR + 4 * g];
            frag_u Bh, Bl;
            #pragma unroll
            for (int d = 0; d < 4; d++) { Bh.u[d] = bh[d]; Bl.u[d] = bl[d]; }
            #pragma unroll
            for (int t = 0; t < 2; t++) {
                acc[ti][t] = __builtin_amdgcn_mfma_f32_16x16x32_bf16(Ah[t].s, Bh.s, acc[ti][t], 0, 0, 0);
                acc[ti][t] = __builtin_amdgcn_mfma_f32_16x16x32_bf16(Al[t].s, Bh.s, acc[ti][t], 0, 0, 0);
                acc[ti][t] = __builtin_amdgcn_mfma_f32_16x16x32_bf16(Ah[t].s, Bl.s, acc[ti][t], 0, 0, 0);
            }
        }
        __syncthreads();
    }

    // ---- pool LDS accumulators (alias dead hid_hi): col 768 | row 32 | mat 8 | max 32
    float* col_lds = (float*)hid_hi;
    float* row_lds = col_lds + 768;
    float* mat_lds = row_lds + 32;
    unsigned* max_lds = (unsigned*)(mat_lds + 8);
    if (do_pool) {
        for (int i = tid; i < 768 + 32 + 8 + 32; i += 256) col_lds[i] = 0.f;
        __syncthreads();
    }

    int R = rows_len[bc], L = cols_len[bc];
    int a0 = base / NW;
    float psum[2][4] = {{0.f, 0.f, 0.f, 0.f}, {0.f, 0.f, 0.f, 0.f}};
    float matp[2] = {0.f, 0.f};
    float mxp[2][4];
    #pragma unroll
    for (int t = 0; t < 2; t++)
        #pragma unroll
        for (int r = 0; r < 4; r++) mxp[t][r] = -FLT_MAX;

    #pragma unroll
    for (int ti = 0; ti < 4; ti++) {
        int el = (wv * 4 + ti) * 16 + c16;
        int ee = base + el;
        int aa = ee / NW, ww = ee - aa * NW;
        float mk = (aa < R && ww < L) ? 1.f : 0.f;
        float rowv[2];
        #pragma unroll
        for (int t = 0; t < 2; t++) {
            #pragma unroll
            for (int r = 0; r < 4; r++) {
                int f = 4 * g + r + 16 * t;
                float* ad = hp + (size_t)f * AW + ee;
                float hv = (*ad + acc[ti][t][r]) * mk;
                if (!last) *ad = hv;
                else       psum[t][r] = fmaf(hv, hv, psum[t][r]);
                if (do_pool) {
                    mxp[t][r] = fmaxf(mxp[t][r], hv);
                    if (r == 1)      rowv[t] = __sinf(hv);
                    else if (r == 2) atomicAdd(&col_lds[ww * 8 + g + 4 * t], __sinf(hv));
                    else if (r == 3) matp[t] += __sinf(hv);
                }
            }
        }
        if (do_pool) {
            #pragma unroll
            for (int t = 0; t < 2; t++) {
                float v = rowv[t];
                v += __shfl_xor(v, 1, 64);
                v += __shfl_xor(v, 2, 64);
                v += __shfl_xor(v, 4, 64);
                v += __shfl_xor(v, 8, 64);
                if (c16 == 0) atomicAdd(&row_lds[(aa - a0) * 8 + g + 4 * t], v);
            }
        }
    }

    if (do_pool) {
        #pragma unroll
        for (int t = 0; t < 2; t++) {
            float v = matp[t];
            v += __shfl_xor(v, 1, 64);
            v += __shfl_xor(v, 2, 64);
            v += __shfl_xor(v, 4, 64);
            v += __shfl_xor(v, 8, 64);
            if (c16 == 0) atomicAdd(&mat_lds[g + 4 * t], v);
            #pragma unroll
            for (int r = 0; r < 4; r++) {
                float m = mxp[t][r];
                m = fmaxf(m, __shfl_xor(m, 1, 64));
                m = fmaxf(m, __shfl_xor(m, 2, 64));
                m = fmaxf(m, __shfl_xor(m, 4, 64));
                m = fmaxf(m, __shfl_xor(m, 8, 64));
                if (c16 == 0) atomicMax(&max_lds[4 * g + r + 16 * t], fkey(m));
            }
        }
        __syncthreads();
        if (tid < 32) {
            int ar = a0 + (tid >> 3);
            if (ar < NA) atomicAdd(&rowsum[(bc * NA + ar) * 8 + (tid & 7)], row_lds[tid]);
        }
        if (tid < 8) atomicAdd(&matsum[bc * 8 + tid], mat_lds[tid]);
        if (tid >= 32 && tid < 64) atomicMax(&cmax_key[bc * NF + tid - 32], max_lds[tid - 32]);
        size_t pbase = ((size_t)bc * 36 + blk36) * (NW * 8);
        for (int i = tid; i < NW * 8; i += 256) colpart[pbase + i] = col_lds[i];
    }

    if (last) {
        float* sq_lds = (float*)hid_hi;
        if (tid < NF) sq_lds[tid] = 0.f;
        __syncthreads();
        #pragma unroll
        for (int t = 0; t < 2; t++) {
            #pragma unroll
            for (int r = 0; r < 4; r++) {
                float v = psum[t][r];
                v += __shfl_xor(v, 1, 64);
                v += __shfl_xor(v, 2, 64);
                v += __shfl_xor(v, 4, 64);
                v += __shfl_xor(v, 8, 64);
                if (c16 == 0) atomicAdd(&sq_lds[4 * g + r + 16 * t], v);
            }
        }
        __syncthreads();
        if (tid < NF) atomicAdd(&sqsum[bc * NF + tid], sq_lds[tid]);
    }
}

// ---------------------------------------------------------------- final: rms from sqsum + mean-over-C + MLP + tanh
__global__ __launch_bounds__(64) void out_kernel(
    const float* __restrict__ sqsum, const int* __restrict__ rows_len,
    const int* __restrict__ cols_len, const float* __restrict__ w1,
    const float* __restrict__ b1, const float* __restrict__ w2,
    const float* __restrict__ b2, float* __restrict__ out)
{
    int b = threadIdx.x;
    if (b >= NB) return;
    float hm[NF];
    #pragma unroll
    for (int f = 0; f < NF; f++) hm[f] = 0.f;
    for (int c = 0; c < NC; c++) {
        int bc = b * NC + c;
        float n = (float)(rows_len[bc] * cols_len[bc]);
        float rdn = 1.f / fmaxf(n, 1e-12f);
        #pragma unroll
        for (int f = 0; f < NF; f++) {
            float q = fmaxf(sqsum[bc * NF + f], 1e-20f);
            hm[f] += sqrtf(q * rdn);
        }
    }
    #pragma unroll
    for (int f = 0; f < NF; f++) hm[f] *= (1.f / (float)NC);

    float o0 = b2[0], o1 = b2[1];
    for (int j = 0; j < NHID; j++) {
        float v = b1[j];
        #pragma unroll
        for (int f = 0; f < NF; f++) v = fmaf(hm[f], w1[f * NHID + j], v);
        v = fmaxf(v, 0.f);
        o0 = fmaf(v, w2[j * 2 + 0], o0);
        o1 = fmaf(v, w2[j * 2 + 1], o1);
    }
    out[b * 2 + 0] = 8.f * tanhf(o0);
    out[b * 2 + 1] = 8.f * tanhf(o1);
}

// ---------------------------------------------------------------- launcher
extern "C" void kernel_launch(void* const* d_in, const int* in_sizes, int n_in,
                              void* d_out, int out_size, void* d_ws, size_t ws_size,
                              hipStream_t stream)
{
    const float* x    = (const float*)d_in[0];
    const int* rl     = (const int*)d_in[1];
    const int* cl     = (const int*)d_in[2];
    const float* t0w1 = (const float*)d_in[3];
    const float* t0b1 = (const float*)d_in[4];
    const float* t0w2 = (const float*)d_in[5];
    const float* t0b2 = (const float*)d_in[6];
    const float* tw1  = (const float*)d_in[7];
    const float* tb1  = (const float*)d_in[8];
    const float* tw2  = (const float*)d_in[9];
    const float* tb2  = (const float*)d_in[10];
    const float* ow1  = (const float*)d_in[11];
    const float* ob1  = (const float*)d_in[12];
    const float* ow2  = (const float*)d_in[13];
    const float* ob2  = (const float*)d_in[14];
    float* out = (float*)d_out;

    float* ws    = (float*)d_ws;
    float* h     = ws;                               // NEL*NF
    float* stats = h + NEL * NF;                     // 2*NBC
    // --- contiguous accumulator region (single memset per stack) ---
    float*    rowb    = stats + 2 * NBC;             // NBC*NA*8      = 147456
    float*    matb    = rowb + (size_t)NBC * NA * 8; // NBC*8         = 1536
    unsigned* cmxb    = (unsigned*)(matb + NBC * 8); // NBC*NF        = 6144
    float*    colpart = (float*)(cmxb + NBC * NF);   // NBC*36*768    = 5308416
    size_t    accum_floats = (size_t)NBC * NA * 8 + NBC * 8 + NBC * NF
                           + (size_t)NBC * 36 * (NW * 8);
    // --- rest ---
    float* colb  = colpart + (size_t)NBC * 36 * (NW * 8);  // NBC*NW*8 (direct, stack 0)
    float* sqb   = colb + (size_t)NBC * NW * 8;      // NBC*NF
    float* w1tb  = sqb + NBC * NF;                   // 4*NHID*24
    float* rowcb = w1tb + 4 * NHID * 24;             // NBC*NHID*NA
    float* colcb = rowcb + (size_t)NBC * NHID * NA;  // NBC*NHID*NW
    unsigned short* w2bfb = (unsigned short*)(colcb + (size_t)NBC * NHID * NW);

    hipMemsetAsync(sqb, 0, NBC * NF * sizeof(float), stream);
    stats_kernel<<<NBC, 256, 0, stream>>>(x, rl, cl, stats);
    prep_kernel<<<(4 * NHID * 24 + 255) / 256, 256, 0, stream>>>(tw1, w1tb);
    prep2_kernel<<<(4 * NF * NHID + 255) / 256, 256, 0, stream>>>(tw2, w2bfb);
    t0_kernel<<<(int)(NEL / 512), 256, 0, stream>>>(x, rl, cl, stats,
                                                    t0w1, t0b1, t0w2, t0b2, h);
    pool_kernel<<<NBC * NF, 256, 0, stream>>>(h, rowb, colb, matb, cmxb);
    for (int s = 0; s < 4; s++) {
        precomp_kernel<<<NBC, 256, 0, stream>>>(rowb, colb, colpart, matb, cmxb,
            tw1 + (size_t)s * 64 * NHID, tb1 + s * NHID, rowcb, colcb,
            (s == 0) ? 0 : 36);
        if (s < 3)
            hipMemsetAsync(rowb, 0, accum_floats * sizeof(float), stream);
        mlp_kernel<<<NBC * 36, 256, 0, stream>>>(h, rowcb, colcb, rl, cl,
            w1tb + (size_t)s * NHID * 24,
            w2bfb + (size_t)s * (2 * NF * NHID),
            tb2 + s * NF, sqb, rowb, colpart, matb, cmxb,
            (s == 3) ? 1 : 0, (s < 3) ? 1 : 0);
    }
    out_kernel<<<1, 64, 0, stream>>>(sqb, rl, cl, ow1, ob1, ow2, ob2, out);
}

// Round 12
// 1383.248 us; speedup vs baseline: 1.2611x; 1.1460x over previous
//
#include <hip/hip_runtime.h>
#include <math.h>
#include <float.h>

#define NB 8
#define NC 24
#define NA 96
#define NW 96
#define NF 32
#define NHID 128
#define AW (NA*NW)           // 9216
#define NBC (NB*NC)          // 192
#define NEL ((size_t)NBC*AW) // 1769472
#define HSTR 17              // hid LDS row stride in dwords (v10-proven: 210us)

// packed fp32: <2 x float> fma -> v_pk_fma_f32 on gfx90a+/gfx950
typedef float v2f __attribute__((ext_vector_type(2)));
typedef float f32x4 __attribute__((ext_vector_type(4)));
typedef short short8_t __attribute__((ext_vector_type(8)));
#ifndef __has_builtin
#define __has_builtin(x) 0
#endif
#if __has_builtin(__builtin_elementwise_fma)
#define PKFMA(a,b,c) __builtin_elementwise_fma((a),(b),(c))
#else
#define PKFMA(a,b,c) ((a)*(b)+(c))
#endif

union frag_u { unsigned int u[4]; short8_t s; };

__device__ __forceinline__ unsigned short bf16rne(float x) {
    unsigned int u = __float_as_uint(x);
    unsigned int r = u + 0x7fffu + ((u >> 16) & 1u);
    return (unsigned short)(r >> 16);
}
// monotone float<->uint key (handles negatives); key(x1)<key(x2) iff x1<x2
__device__ __forceinline__ unsigned fkey(float x) {
    unsigned u = __float_as_uint(x);
    return (u >> 31) ? ~u : (u | 0x80000000u);
}
__device__ __forceinline__ float funkey(unsigned k) {
    return (k >> 31) ? __uint_as_float(k ^ 0x80000000u) : __uint_as_float(~k);
}

// ---------------------------------------------------------------- stats
__global__ __launch_bounds__(256) void stats_kernel(
    const float* __restrict__ x, const int* __restrict__ rows_len,
    const int* __restrict__ cols_len, float* __restrict__ stats)
{
    int bc = blockIdx.x;
    int R = rows_len[bc], L = cols_len[bc];
    const float* xp = x + (size_t)bc * AW;
    int n = R * L;
    float sx = 0.f, sxx = 0.f;
    for (int i = threadIdx.x; i < n; i += 256) {
        int a = i / L, w = i - a * L;
        float v = xp[a * NW + w];
        sx += v;
        sxx = fmaf(v, v, sxx);
    }
    __shared__ float r1[256], r2[256];
    r1[threadIdx.x] = sx; r2[threadIdx.x] = sxx;
    __syncthreads();
    for (int s = 128; s > 0; s >>= 1) {
        if (threadIdx.x < s) {
            r1[threadIdx.x] += r1[threadIdx.x + s];
            r2[threadIdx.x] += r2[threadIdx.x + s];
        }
        __syncthreads();
    }
    if (threadIdx.x == 0) {
        float fn = (float)n;
        float mean = r1[0] / fn;
        float var = fmaxf((r2[0] - r1[0] * r1[0] / fn) / (fn - 1.f), 0.f);
        float sd = fmaxf(sqrtf(var), 1e-12f);
        stats[2 * bc] = mean;
        stats[2 * bc + 1] = 1.f / sd;
    }
}

// ---------------------------------------------------------------- prep: transpose first 24 rows of each stack's W1
__global__ __launch_bounds__(256) void prep_kernel(
    const float* __restrict__ tw1, float* __restrict__ w1t)
{
    int i = blockIdx.x * 256 + threadIdx.x;     // [s][j][t]
    if (i >= 4 * NHID * 24) return;
    int s = i / (NHID * 24), r = i % (NHID * 24);
    int j = r / 24, t = r % 24;
    w1t[i] = tw1[(size_t)s * 64 * NHID + t * NHID + j];
}

// ---------------------------------------------------------------- prep2: split W2^T into bf16 hi/lo (per stack)
__global__ __launch_bounds__(256) void prep2_kernel(
    const float* __restrict__ tw2, unsigned short* __restrict__ w2bf)
{
    int i = blockIdx.x * 256 + threadIdx.x;
    if (i >= 4 * NF * NHID) return;
    int s = i / (NF * NHID), r = i % (NF * NHID);
    int f = r / NHID, j = r % NHID;
    float v = tw2[((size_t)s * NHID + j) * NF + f];
    unsigned short hi = bf16rne(v);
    float hf = __uint_as_float(((unsigned int)hi) << 16);
    unsigned short lo = bf16rne(v - hf);
    size_t base = (size_t)s * (2 * NF * NHID) + (size_t)f * NHID + j;
    w2bf[base] = hi;
    w2bf[base + NF * NHID] = lo;
}

// ---------------------------------------------------------------- t0 MLP (1->128->32), packed-f accumulation
__global__ __launch_bounds__(256) void t0_kernel(
    const float* __restrict__ x, const int* __restrict__ rows_len,
    const int* __restrict__ cols_len, const float* __restrict__ stats,
    const float* __restrict__ w1, const float* __restrict__ b1,
    const float* __restrict__ w2, const float* __restrict__ b2,
    float* __restrict__ h)
{
    int tid = threadIdx.x;
    int bc = blockIdx.x / 18;
    int base = (blockIdx.x % 18) * 512;
    int R = rows_len[bc], L = cols_len[bc];
    float mean = stats[2 * bc], rstd = stats[2 * bc + 1];

    int eA = base + tid, eB = eA + 256;
    int aA = eA / NW, wA = eA % NW;
    int aB = eB / NW, wB = eB % NW;
    bool vA = (aA < R) && (wA < L);
    bool vB = (aB < R) && (wB < L);
    size_t gA = (size_t)bc * AW + eA;
    float xA = vA ? (x[gA] - mean) * rstd : 0.f;
    float xB = vB ? (x[gA + 256] - mean) * rstd : 0.f;

    v2f oA[16], oB[16];
    const v2f* b22 = (const v2f*)b2;
    #pragma unroll
    for (int i = 0; i < 16; i++) { v2f bb = b22[i]; oA[i] = bb; oB[i] = bb; }
    for (int j = 0; j < NHID; j++) {
        float hA = fmaxf(fmaf(xA, w1[j], b1[j]), 0.f);
        float hB = fmaxf(fmaf(xB, w1[j], b1[j]), 0.f);
        const v2f* wr = (const v2f*)&w2[j * NF];
        v2f hA2 = {hA, hA}, hB2 = {hB, hB};
        #pragma unroll
        for (int i = 0; i < 16; i++) {
            v2f q = wr[i];
            oA[i] = PKFMA(hA2, q, oA[i]);
            oB[i] = PKFMA(hB2, q, oB[i]);
        }
    }
    float mA = vA ? 1.f : 0.f, mB = vB ? 1.f : 0.f;
    float* hp = h + (size_t)bc * NF * AW;
    #pragma unroll
    for (int f = 0; f < NF; f++) {
        hp[(size_t)f * AW + eA] = oA[f >> 1][f & 1] * mA;
        hp[(size_t)f * AW + eB] = oB[f >> 1][f & 1] * mB;
    }
}

// ---------------------------------------------------------------- pool (only for stack 0, after t0)
__global__ __launch_bounds__(256) void pool_kernel(
    const float* __restrict__ h, float* __restrict__ rowsum,
    float* __restrict__ colsum, float* __restrict__ matsum,
    unsigned* __restrict__ cmax_key)
{
    __shared__ float sred[4];
    __shared__ float scol[4][96];
    int blk = blockIdx.x;            // bc*32 + f
    int bc = blk >> 5, f = blk & 31;
    const float* p = h + (size_t)blk * AW;
    int tid = threadIdx.x;
    int lane = tid & 63, wv = tid >> 6;

    float mx = -FLT_MAX;
    for (int i = tid; i < AW; i += 256) mx = fmaxf(mx, p[i]);
    #pragma unroll
    for (int off = 32; off >= 1; off >>= 1) mx = fmaxf(mx, __shfl_xor(mx, off, 64));
    if (lane == 0) sred[wv] = mx;
    __syncthreads();
    if (tid == 0)
        cmax_key[bc * NF + f] =
            fkey(fmaxf(fmaxf(sred[0], sred[1]), fmaxf(sred[2], sred[3])));

    int mode = f & 3, k = f >> 2;
    if (mode == 1) {
        for (int r = 0; r < 24; r++) {
            int a = wv + 4 * r;
            float v1 = p[a * NW + lane];
            float s = __sinf(v1);
            if (lane < 32) s += __sinf(p[a * NW + 64 + lane]);
            #pragma unroll
            for (int off = 32; off >= 1; off >>= 1) s += __shfl_xor(s, off, 64);
            if (lane == 0) rowsum[(bc * NA + a) * 8 + k] = s;
        }
    } else if (mode == 2) {
        float acc0 = 0.f, acc1 = 0.f;
        for (int r = 0; r < 24; r++) {
            int a = wv + 4 * r;
            acc0 += __sinf(p[a * NW + lane]);
            if (lane < 32) acc1 += __sinf(p[a * NW + 64 + lane]);
        }
        scol[wv][lane] = acc0;
        if (lane < 32) scol[wv][64 + lane] = acc1;
        __syncthreads();
        if (tid < 96)
            colsum[(bc * NW + tid) * 8 + k] =
                scol[0][tid] + scol[1][tid] + scol[2][tid] + scol[3][tid];
    } else if (mode == 3) {
        float s = 0.f;
        for (int i = tid; i < AW; i += 256) s += __sinf(p[i]);
        #pragma unroll
        for (int off = 32; off >= 1; off >>= 1) s += __shfl_xor(s, off, 64);
        __syncthreads();
        if (lane == 0) sred[wv] = s;
        __syncthreads();
        if (tid == 0) matsum[bc * 8 + k] = sred[0] + sred[1] + sred[2] + sred[3];
    }
}

// ---------------------------------------------------------------- precompute per-(bc): rowc[j][a], colc[j][w]
__global__ __launch_bounds__(256) void precomp_kernel(
    const float* __restrict__ rowsum, const float* __restrict__ colsum,
    const float* __restrict__ matsum, const unsigned* __restrict__ cmax_key,
    const float* __restrict__ w1, const float* __restrict__ b1,
    float* __restrict__ rowc, float* __restrict__ colc)
{
    __shared__ float sbm[NF];
    __shared__ float sconst[NHID];
    __shared__ float scs[NW * 8];
    int tid = threadIdx.x;
    int bc = blockIdx.x, b = bc / NC;

    for (int i = tid; i < NW * 8; i += 256) scs[i] = colsum[bc * NW * 8 + i];
    if (tid < NF) {
        unsigned km = cmax_key[(b * NC) * NF + tid];
        for (int c = 1; c < NC; c++) {
            unsigned kc = cmax_key[(b * NC + c) * NF + tid];
            km = (kc > km) ? kc : km;
        }
        sbm[tid] = funkey(km);
    }
    __syncthreads();
    if (tid < NHID) {
        float v = b1[tid];
        const float* mp = matsum + bc * 8;
        #pragma unroll
        for (int k = 0; k < 8; k++) v = fmaf(mp[k], w1[(24 + k) * NHID + tid], v);
        #pragma unroll
        for (int f = 0; f < NF; f++) v = fmaf(sbm[f], w1[(32 + f) * NHID + tid], v);
        sconst[tid] = v;
    }
    __syncthreads();
    for (int i = tid; i < NHID * NA; i += 256) {
        int j = i / NA, aa = i - j * NA;
        const float* rp = rowsum + (bc * NA + aa) * 8;
        float v = sconst[j];
        #pragma unroll
        for (int k = 0; k < 8; k++) v = fmaf(rp[k], w1[(8 + k) * NHID + j], v);
        rowc[(size_t)bc * (NHID * NA) + i] = v;
    }
    for (int i = tid; i < NHID * NW; i += 256) {
        int j = i / NW, ww = i - j * NW;
        float v = 0.f;
        #pragma unroll
        for (int k = 0; k < 8; k++) v = fmaf(scs[ww * 8 + k], w1[(16 + k) * NHID + j], v);
        colc[(size_t)bc * (NHID * NW) + i] = v;
    }
}

// ---------------------------------------------------------------- stack MLP v13: v10 core + fused pool epilogue (de-taxed)
// vs v12 (288us): (1) col_lds stride 9 -> conflict-free LDS atomics;
// (2) colpart removed -> col partial flushed with 3 global atomicAdd/thread
//     straight into colsum (36-way contention over 147K addrs, L2-trivial);
// (3) memset region shrinks 22MB -> 1.2MB (colpart was never accumulated).
__global__ __launch_bounds__(256, 4) void mlp_kernel(
    float* __restrict__ h, const float* __restrict__ rowc,
    const float* __restrict__ colc, const int* __restrict__ rows_len,
    const int* __restrict__ cols_len, const float* __restrict__ w1t,
    const unsigned short* __restrict__ w2bf, const float* __restrict__ b2,
    float* __restrict__ sqsum, float* __restrict__ rowsum,
    float* __restrict__ colsum, float* __restrict__ matsum,
    unsigned* __restrict__ cmax_key, int last, int do_pool)
{
    __shared__ unsigned int hid_hi[256 * HSTR];  // 17.4 KB
    __shared__ unsigned int hid_lo[256 * HSTR];  // 17.4 KB

    int tid = threadIdx.x;
    int bc = blockIdx.x / 36;
    int blk36 = blockIdx.x % 36;
    int base = blk36 * 256;
    int lane = tid & 63, wv = tid >> 6;
    int g = lane >> 4, c16 = lane & 15;

    int e = base + tid;
    int a = e / NW, wc = e - a * NW;
    float* hp = h + (size_t)bc * NF * AW;

    float p[8];
    #pragma unroll
    for (int k = 0; k < 8; k++) p[k] = __sinf(hp[(size_t)(4 * k) * AW + e]);
    v2f p2[4];
    #pragma unroll
    for (int t = 0; t < 4; t++) p2[t] = (v2f){p[2 * t], p[2 * t + 1]};

    const unsigned short* w2hi = w2bf;
    const unsigned short* w2lo = w2bf + NF * NHID;

    f32x4 acc[4][2];
    #pragma unroll
    for (int t = 0; t < 2; t++) {
        f32x4 bb = *(const f32x4*)(b2 + 16 * t + 4 * g);
        #pragma unroll
        for (int ti = 0; ti < 4; ti++) acc[ti][t] = bb;
    }

    const float* rcr = rowc + (size_t)bc * (NHID * NA);
    const float* rcc = colc + (size_t)bc * (NHID * NW);

    for (int w = 0; w < 4; w++) {
        int jw = 32 * w;
        frag_u Ah[2], Al[2];
        #pragma unroll
        for (int t = 0; t < 2; t++) {
            size_t off = (size_t)(c16 + 16 * t) * NHID + jw + 8 * g;
            const unsigned int* ph = (const unsigned int*)(w2hi + off);
            const unsigned int* pl = (const unsigned int*)(w2lo + off);
            #pragma unroll
            for (int d = 0; d < 4; d++) { Ah[t].u[d] = ph[d]; Al[t].u[d] = pl[d]; }
        }

        #pragma unroll 4
        for (int jp = 0; jp < 16; jp++) {
            int jl = 2 * jp;
            const v2f* w1r0 = (const v2f*)(w1t + (size_t)(jw + jl) * 24);
            const v2f* w1r1 = w1r0 + 12;
            v2f u0 = {rcr[(size_t)(jw + jl) * NA + a], rcc[(size_t)(jw + jl) * NW + wc]};
            v2f u1 = {rcr[(size_t)(jw + jl + 1) * NA + a], rcc[(size_t)(jw + jl + 1) * NW + wc]};
            #pragma unroll
            for (int t = 0; t < 4; t++) {
                u0 = PKFMA(p2[t], w1r0[t], u0);
                u1 = PKFMA(p2[t], w1r1[t], u1);
            }
            float v0 = fmaxf(u0.x + u0.y, 0.f);
            float v1 = fmaxf(u1.x + u1.y, 0.f);
            unsigned int hi, lo;
            asm("v_cvt_pk_bf16_f32 %0, %1, %2" : "=v"(hi) : "v"(v0), "v"(v1));
            float h0 = __uint_as_float(hi << 16);
            float h1 = __uint_as_float(hi & 0xffff0000u);
            float l0 = v0 - h0, l1 = v1 - h1;
            asm("v_cvt_pk_bf16_f32 %0, %1, %2" : "=v"(lo) : "v"(l0), "v"(l1));
            hid_hi[tid * HSTR + jp] = hi;
            hid_lo[tid * HSTR + jp] = lo;
        }
        __syncthreads();

        #pragma unroll
        for (int ti = 0; ti < 4; ti++) {
            int el = (wv * 4 + ti) * 16 + c16;
            const unsigned int* bh = &hid_hi[el * HSTR + 4 * g];
            const unsigned int* bl = &hid_lo[el * HSTR + 4 * g];
            frag_u Bh, Bl;
            #pragma unroll
            for (int d = 0; d < 4; d++) { Bh.u[d] = bh[d]; Bl.u[d] = bl[d]; }
            #pragma unroll
            for (int t = 0; t < 2; t++) {
                acc[ti][t] = __builtin_amdgcn_mfma_f32_16x16x32_bf16(Ah[t].s, Bh.s, acc[ti][t], 0, 0, 0);
                acc[ti][t] = __builtin_amdgcn_mfma_f32_16x16x32_bf16(Al[t].s, Bh.s, acc[ti][t], 0, 0, 0);
                acc[ti][t] = __builtin_amdgcn_mfma_f32_16x16x32_bf16(Ah[t].s, Bl.s, acc[ti][t], 0, 0, 0);
            }
        }
        __syncthreads();
    }

    // ---- pool LDS accumulators (alias dead hid_hi):
    // col 96*9 (stride-9 -> conflict-free atomics) | row 32 | mat 8 | max 32
    float* col_lds = (float*)hid_hi;
    float* row_lds = col_lds + 96 * 9;
    float* mat_lds = row_lds + 32;
    unsigned* max_lds = (unsigned*)(mat_lds + 8);
    if (do_pool) {
        for (int i = tid; i < 96 * 9 + 32 + 8 + 32; i += 256) col_lds[i] = 0.f;
        __syncthreads();
    }

    int R = rows_len[bc], L = cols_len[bc];
    int a0 = base / NW;
    float psum[2][4] = {{0.f, 0.f, 0.f, 0.f}, {0.f, 0.f, 0.f, 0.f}};
    float matp[2] = {0.f, 0.f};
    float mxp[2][4];
    #pragma unroll
    for (int t = 0; t < 2; t++)
        #pragma unroll
        for (int r = 0; r < 4; r++) mxp[t][r] = -FLT_MAX;

    #pragma unroll
    for (int ti = 0; ti < 4; ti++) {
        int el = (wv * 4 + ti) * 16 + c16;
        int ee = base + el;
        int aa = ee / NW, ww = ee - aa * NW;
        float mk = (aa < R && ww < L) ? 1.f : 0.f;
        float rowv[2];
        #pragma unroll
        for (int t = 0; t < 2; t++) {
            #pragma unroll
            for (int r = 0; r < 4; r++) {
                int f = 4 * g + r + 16 * t;
                float* ad = hp + (size_t)f * AW + ee;
                float hv = (*ad + acc[ti][t][r]) * mk;
                if (!last) *ad = hv;
                else       psum[t][r] = fmaf(hv, hv, psum[t][r]);
                if (do_pool) {
                    mxp[t][r] = fmaxf(mxp[t][r], hv);
                    if (r == 1)      rowv[t] = __sinf(hv);
                    else if (r == 2) atomicAdd(&col_lds[ww * 9 + g + 4 * t], __sinf(hv));
                    else if (r == 3) matp[t] += __sinf(hv);
                }
            }
        }
        if (do_pool) {
            #pragma unroll
            for (int t = 0; t < 2; t++) {
                float v = rowv[t];
                v += __shfl_xor(v, 1, 64);
                v += __shfl_xor(v, 2, 64);
                v += __shfl_xor(v, 4, 64);
                v += __shfl_xor(v, 8, 64);
                if (c16 == 0) atomicAdd(&row_lds[(aa - a0) * 8 + g + 4 * t], v);
            }
        }
    }

    if (do_pool) {
        #pragma unroll
        for (int t = 0; t < 2; t++) {
            float v = matp[t];
            v += __shfl_xor(v, 1, 64);
            v += __shfl_xor(v, 2, 64);
            v += __shfl_xor(v, 4, 64);
            v += __shfl_xor(v, 8, 64);
            if (c16 == 0) atomicAdd(&mat_lds[g + 4 * t], v);
            #pragma unroll
            for (int r = 0; r < 4; r++) {
                float m = mxp[t][r];
                m = fmaxf(m, __shfl_xor(m, 1, 64));
                m = fmaxf(m, __shfl_xor(m, 2, 64));
                m = fmaxf(m, __shfl_xor(m, 4, 64));
                m = fmaxf(m, __shfl_xor(m, 8, 64));
                if (c16 == 0) atomicMax(&max_lds[4 * g + r + 16 * t], fkey(m));
            }
        }
        __syncthreads();
        if (tid < 32) {
            int ar = a0 + (tid >> 3);
            if (ar < NA) atomicAdd(&rowsum[(bc * NA + ar) * 8 + (tid & 7)], row_lds[tid]);
        }
        if (tid < 8) atomicAdd(&matsum[bc * 8 + tid], mat_lds[tid]);
        if (tid >= 32 && tid < 64) atomicMax(&cmax_key[bc * NF + tid - 32], max_lds[tid - 32]);
        for (int i = tid; i < NW * 8; i += 256)
            atomicAdd(&colsum[bc * NW * 8 + i], col_lds[(i >> 3) * 9 + (i & 7)]);
    }

    if (last) {
        float* sq_lds = (float*)hid_hi;
        if (tid < NF) sq_lds[tid] = 0.f;
        __syncthreads();
        #pragma unroll
        for (int t = 0; t < 2; t++) {
            #pragma unroll
            for (int r = 0; r < 4; r++) {
                float v = psum[t][r];
                v += __shfl_xor(v, 1, 64);
                v += __shfl_xor(v, 2, 64);
                v += __shfl_xor(v, 4, 64);
                v += __shfl_xor(v, 8, 64);
                if (c16 == 0) atomicAdd(&sq_lds[4 * g + r + 16 * t], v);
            }
        }
        __syncthreads();
        if (tid < NF) atomicAdd(&sqsum[bc * NF + tid], sq_lds[tid]);
    }
}

// ---------------------------------------------------------------- final: rms from sqsum + mean-over-C + MLP + tanh
__global__ __launch_bounds__(64) void out_kernel(
    const float* __restrict__ sqsum, const int* __restrict__ rows_len,
    const int* __restrict__ cols_len, const float* __restrict__ w1,
    const float* __restrict__ b1, const float* __restrict__ w2,
    const float* __restrict__ b2, float* __restrict__ out)
{
    int b = threadIdx.x;
    if (b >= NB) return;
    float hm[NF];
    #pragma unroll
    for (int f = 0; f < NF; f++) hm[f] = 0.f;
    for (int c = 0; c < NC; c++) {
        int bc = b * NC + c;
        float n = (float)(rows_len[bc] * cols_len[bc]);
        float rdn = 1.f / fmaxf(n, 1e-12f);
        #pragma unroll
        for (int f = 0; f < NF; f++) {
            float q = fmaxf(sqsum[bc * NF + f], 1e-20f);
            hm[f] += sqrtf(q * rdn);
        }
    }
    #pragma unroll
    for (int f = 0; f < NF; f++) hm[f] *= (1.f / (float)NC);

    float o0 = b2[0], o1 = b2[1];
    for (int j = 0; j < NHID; j++) {
        float v = b1[j];
        #pragma unroll
        for (int f = 0; f < NF; f++) v = fmaf(hm[f], w1[f * NHID + j], v);
        v = fmaxf(v, 0.f);
        o0 = fmaf(v, w2[j * 2 + 0], o0);
        o1 = fmaf(v, w2[j * 2 + 1], o1);
    }
    out[b * 2 + 0] = 8.f * tanhf(o0);
    out[b * 2 + 1] = 8.f * tanhf(o1);
}

// ---------------------------------------------------------------- launcher
extern "C" void kernel_launch(void* const* d_in, const int* in_sizes, int n_in,
                              void* d_out, int out_size, void* d_ws, size_t ws_size,
                              hipStream_t stream)
{
    const float* x    = (const float*)d_in[0];
    const int* rl     = (const int*)d_in[1];
    const int* cl     = (const int*)d_in[2];
    const float* t0w1 = (const float*)d_in[3];
    const float* t0b1 = (const float*)d_in[4];
    const float* t0w2 = (const float*)d_in[5];
    const float* t0b2 = (const float*)d_in[6];
    const float* tw1  = (const float*)d_in[7];
    const float* tb1  = (const float*)d_in[8];
    const float* tw2  = (const float*)d_in[9];
    const float* tb2  = (const float*)d_in[10];
    const float* ow1  = (const float*)d_in[11];
    const float* ob1  = (const float*)d_in[12];
    const float* ow2  = (const float*)d_in[13];
    const float* ob2  = (const float*)d_in[14];
    float* out = (float*)d_out;

    float* ws    = (float*)d_ws;
    float* h     = ws;                               // NEL*NF
    float* stats = h + NEL * NF;                     // 2*NBC
    // --- contiguous accumulator region (single small memset per stack) ---
    float*    rowb = stats + 2 * NBC;                // NBC*NA*8 = 147456
    float*    matb = rowb + (size_t)NBC * NA * 8;    // NBC*8    = 1536
    unsigned* cmxb = (unsigned*)(matb + NBC * 8);    // NBC*NF   = 6144
    float*    colb = (float*)(cmxb + NBC * NF);      // NBC*NW*8 = 147456
    size_t    accum_floats = (size_t)NBC * NA * 8 + NBC * 8 + NBC * NF
                           + (size_t)NBC * NW * 8;   // 302592 floats = 1.2 MB
    // --- rest ---
    float* sqb   = colb + (size_t)NBC * NW * 8;      // NBC*NF
    float* w1tb  = sqb + NBC * NF;                   // 4*NHID*24
    float* rowcb = w1tb + 4 * NHID * 24;             // NBC*NHID*NA
    float* colcb = rowcb + (size_t)NBC * NHID * NA;  // NBC*NHID*NW
    unsigned short* w2bfb = (unsigned short*)(colcb + (size_t)NBC * NHID * NW);

    hipMemsetAsync(sqb, 0, NBC * NF * sizeof(float), stream);
    stats_kernel<<<NBC, 256, 0, stream>>>(x, rl, cl, stats);
    prep_kernel<<<(4 * NHID * 24 + 255) / 256, 256, 0, stream>>>(tw1, w1tb);
    prep2_kernel<<<(4 * NF * NHID + 255) / 256, 256, 0, stream>>>(tw2, w2bfb);
    t0_kernel<<<(int)(NEL / 512), 256, 0, stream>>>(x, rl, cl, stats,
                                                    t0w1, t0b1, t0w2, t0b2, h);
    pool_kernel<<<NBC * NF, 256, 0, stream>>>(h, rowb, colb, matb, cmxb);
    for (int s = 0; s < 4; s++) {
        precomp_kernel<<<NBC, 256, 0, stream>>>(rowb, colb, matb, cmxb,
            tw1 + (size_t)s * 64 * NHID, tb1 + s * NHID, rowcb, colcb);
        if (s < 3)
            hipMemsetAsync(rowb, 0, accum_floats * sizeof(float), stream);
        mlp_kernel<<<NBC * 36, 256, 0, stream>>>(h, rowcb, colcb, rl, cl,
            w1tb + (size_t)s * NHID * 24,
            w2bfb + (size_t)s * (2 * NF * NHID),
            tb2 + s * NF, sqb, rowb, colb, matb, cmxb,
            (s == 3) ? 1 : 0, (s < 3) ? 1 : 0);
    }
    out_kernel<<<1, 64, 0, stream>>>(sqb, rl, cl, ow1, ob1, ow2, ob2, out);
}

// Round 13
// 1366.467 us; speedup vs baseline: 1.2766x; 1.0123x over previous
//
#include <hip/hip_runtime.h>
#include <math.h>
#include <float.h>

#define NB 8
#define NC 24
#define NA 96
#define NW 96
#define NF 32
#define NHID 128
#define AW (NA*NW)           // 9216
#define NBC (NB*NC)          // 192
#define NEL ((size_t)NBC*AW) // 1769472
#define HSTR 17              // hid LDS row stride in dwords (v10-proven: 210us)

// packed fp32: <2 x float> fma -> v_pk_fma_f32 on gfx90a+/gfx950
typedef float v2f __attribute__((ext_vector_type(2)));
typedef float f32x4 __attribute__((ext_vector_type(4)));
typedef short short8_t __attribute__((ext_vector_type(8)));
#ifndef __has_builtin
#define __has_builtin(x) 0
#endif
#if __has_builtin(__builtin_elementwise_fma)
#define PKFMA(a,b,c) __builtin_elementwise_fma((a),(b),(c))
#else
#define PKFMA(a,b,c) ((a)*(b)+(c))
#endif

union frag_u { unsigned int u[4]; short8_t s; };

__device__ __forceinline__ unsigned short bf16rne(float x) {
    unsigned int u = __float_as_uint(x);
    unsigned int r = u + 0x7fffu + ((u >> 16) & 1u);
    return (unsigned short)(r >> 16);
}
// monotone float<->uint key (handles negatives); key(x1)<key(x2) iff x1<x2
__device__ __forceinline__ unsigned fkey(float x) {
    unsigned u = __float_as_uint(x);
    return (u >> 31) ? ~u : (u | 0x80000000u);
}
__device__ __forceinline__ float funkey(unsigned k) {
    return (k >> 31) ? __uint_as_float(k ^ 0x80000000u) : __uint_as_float(~k);
}
__device__ __forceinline__ float grp16_sum(float v) {
    v += __shfl_xor(v, 1, 64);
    v += __shfl_xor(v, 2, 64);
    v += __shfl_xor(v, 4, 64);
    v += __shfl_xor(v, 8, 64);
    return v;
}
__device__ __forceinline__ float grp16_max(float v) {
    v = fmaxf(v, __shfl_xor(v, 1, 64));
    v = fmaxf(v, __shfl_xor(v, 2, 64));
    v = fmaxf(v, __shfl_xor(v, 4, 64));
    v = fmaxf(v, __shfl_xor(v, 8, 64));
    return v;
}

// ---------------------------------------------------------------- stats
__global__ __launch_bounds__(256) void stats_kernel(
    const float* __restrict__ x, const int* __restrict__ rows_len,
    const int* __restrict__ cols_len, float* __restrict__ stats)
{
    int bc = blockIdx.x;
    int R = rows_len[bc], L = cols_len[bc];
    const float* xp = x + (size_t)bc * AW;
    int n = R * L;
    float sx = 0.f, sxx = 0.f;
    for (int i = threadIdx.x; i < n; i += 256) {
        int a = i / L, w = i - a * L;
        float v = xp[a * NW + w];
        sx += v;
        sxx = fmaf(v, v, sxx);
    }
    __shared__ float r1[256], r2[256];
    r1[threadIdx.x] = sx; r2[threadIdx.x] = sxx;
    __syncthreads();
    for (int s = 128; s > 0; s >>= 1) {
        if (threadIdx.x < s) {
            r1[threadIdx.x] += r1[threadIdx.x + s];
            r2[threadIdx.x] += r2[threadIdx.x + s];
        }
        __syncthreads();
    }
    if (threadIdx.x == 0) {
        float fn = (float)n;
        float mean = r1[0] / fn;
        float var = fmaxf((r2[0] - r1[0] * r1[0] / fn) / (fn - 1.f), 0.f);
        float sd = fmaxf(sqrtf(var), 1e-12f);
        stats[2 * bc] = mean;
        stats[2 * bc + 1] = 1.f / sd;
    }
}

// ---------------------------------------------------------------- prep: transpose first 24 rows of each stack's W1
__global__ __launch_bounds__(256) void prep_kernel(
    const float* __restrict__ tw1, float* __restrict__ w1t)
{
    int i = blockIdx.x * 256 + threadIdx.x;     // [s][j][t]
    if (i >= 4 * NHID * 24) return;
    int s = i / (NHID * 24), r = i % (NHID * 24);
    int j = r / 24, t = r % 24;
    w1t[i] = tw1[(size_t)s * 64 * NHID + t * NHID + j];
}

// ---------------------------------------------------------------- prep2: split W2^T into bf16 hi/lo (per stack)
__global__ __launch_bounds__(256) void prep2_kernel(
    const float* __restrict__ tw2, unsigned short* __restrict__ w2bf)
{
    int i = blockIdx.x * 256 + threadIdx.x;
    if (i >= 4 * NF * NHID) return;
    int s = i / (NF * NHID), r = i % (NF * NHID);
    int f = r / NHID, j = r % NHID;
    float v = tw2[((size_t)s * NHID + j) * NF + f];
    unsigned short hi = bf16rne(v);
    float hf = __uint_as_float(((unsigned int)hi) << 16);
    unsigned short lo = bf16rne(v - hf);
    size_t base = (size_t)s * (2 * NF * NHID) + (size_t)f * NHID + j;
    w2bf[base] = hi;
    w2bf[base + NF * NHID] = lo;
}

// ---------------------------------------------------------------- t0 MLP (1->128->32) + fused stack-0 pools
// e-mapping remapped to mlp-style row-aligned 16-groups: eA = base+wv*128+lane
// (coalesced identically to the old base+tid), so the c16-group shfl reduce
// works. Epilogue computes rowsum/colsum/matsum/cmax of h = t0-out (the exact
// pools precomp(s=0) needs), LDS-accumulated then atomically flushed — the
// standalone pool_kernel (and its 226 MB re-read) is deleted.
__global__ __launch_bounds__(256, 4) void t0_kernel(
    const float* __restrict__ x, const int* __restrict__ rows_len,
    const int* __restrict__ cols_len, const float* __restrict__ stats,
    const float* __restrict__ w1, const float* __restrict__ b1,
    const float* __restrict__ w2, const float* __restrict__ b2,
    float* __restrict__ h, float* __restrict__ rowsum,
    float* __restrict__ colsum, float* __restrict__ matsum,
    unsigned* __restrict__ cmax_key)
{
    __shared__ float col_lds[96 * 9];   // stride 9 -> conflict-free atomics
    __shared__ float row_lds[8 * 8];    // 6 rows used
    __shared__ float mat_lds[8];
    __shared__ unsigned max_lds[NF];

    int tid = threadIdx.x;
    int bc = blockIdx.x / 18;
    int base = (blockIdx.x % 18) * 512;
    int lane = tid & 63, wv = tid >> 6;
    int c16 = lane & 15;
    int R = rows_len[bc], L = cols_len[bc];
    float mean = stats[2 * bc], rstd = stats[2 * bc + 1];

    for (int i = tid; i < 96 * 9; i += 256) col_lds[i] = 0.f;
    if (tid < 64) row_lds[tid] = 0.f;
    if (tid < 8) mat_lds[tid] = 0.f;
    if (tid < NF) max_lds[tid] = 0u;    // < fkey(x) for all finite x

    int eA = base + wv * 128 + lane;    // 16-aligned tiles, row-safe groups
    int eB = eA + 64;
    int aA = eA / NW, wA = eA % NW;
    int aB = eB / NW, wB = eB % NW;
    bool vA = (aA < R) && (wA < L);
    bool vB = (aB < R) && (wB < L);
    size_t gA = (size_t)bc * AW + eA;
    float xA = vA ? (x[gA] - mean) * rstd : 0.f;
    float xB = vB ? (x[gA + 64] - mean) * rstd : 0.f;

    v2f oA[16], oB[16];
    const v2f* b22 = (const v2f*)b2;
    #pragma unroll
    for (int i = 0; i < 16; i++) { v2f bb = b22[i]; oA[i] = bb; oB[i] = bb; }
    for (int j = 0; j < NHID; j++) {
        float hA = fmaxf(fmaf(xA, w1[j], b1[j]), 0.f);
        float hB = fmaxf(fmaf(xB, w1[j], b1[j]), 0.f);
        const v2f* wr = (const v2f*)&w2[j * NF];
        v2f hA2 = {hA, hA}, hB2 = {hB, hB};
        #pragma unroll
        for (int i = 0; i < 16; i++) {
            v2f q = wr[i];
            oA[i] = PKFMA(hA2, q, oA[i]);
            oB[i] = PKFMA(hB2, q, oB[i]);
        }
    }
    float mA = vA ? 1.f : 0.f, mB = vB ? 1.f : 0.f;
    float* hp = h + (size_t)bc * NF * AW;
    #pragma unroll
    for (int f = 0; f < NF; f++) {
        hp[(size_t)f * AW + eA] = oA[f >> 1][f & 1] * mA;
        hp[(size_t)f * AW + eB] = oB[f >> 1][f & 1] * mB;
    }
    __syncthreads();   // LDS accumulators zeroed

    // ---- fused stack-0 pools from in-register hv
    int a0 = base / NW;
    int rowA = aA - a0, rowB = aB - a0;
    float matp[8];
    #pragma unroll
    for (int k = 0; k < 8; k++) matp[k] = 0.f;

    #pragma unroll
    for (int k = 0; k < 8; k++) {
        // rowsum: f = 4k+1
        int fr = 4 * k + 1;
        float sA = grp16_sum(__sinf(oA[fr >> 1][fr & 1] * mA));
        float sB = grp16_sum(__sinf(oB[fr >> 1][fr & 1] * mB));
        if (c16 == 0) {
            atomicAdd(&row_lds[rowA * 8 + k], sA);
            atomicAdd(&row_lds[rowB * 8 + k], sB);
        }
        // colsum: f = 4k+2 (addresses distinct per lane -> conflict-light)
        int fc = 4 * k + 2;
        atomicAdd(&col_lds[wA * 9 + k], __sinf(oA[fc >> 1][fc & 1] * mA));
        atomicAdd(&col_lds[wB * 9 + k], __sinf(oB[fc >> 1][fc & 1] * mB));
        // matsum: f = 4k+3
        int fm = 4 * k + 3;
        matp[k] = __sinf(oA[fm >> 1][fm & 1] * mA) + __sinf(oB[fm >> 1][fm & 1] * mB);
    }
    #pragma unroll
    for (int k = 0; k < 8; k++) {
        float v = grp16_sum(matp[k]);
        if (c16 == 0) atomicAdd(&mat_lds[k], v);
    }
    #pragma unroll
    for (int f = 0; f < NF; f++) {
        float v = grp16_max(fmaxf(oA[f >> 1][f & 1] * mA, oB[f >> 1][f & 1] * mB));
        if (c16 == 0) atomicMax(&max_lds[f], fkey(v));
    }
    __syncthreads();

    if (tid < 48) {
        int ar = a0 + (tid >> 3);
        if (ar < NA) atomicAdd(&rowsum[(bc * NA + ar) * 8 + (tid & 7)], row_lds[tid]);
    }
    if (tid < 8) atomicAdd(&matsum[bc * 8 + tid], mat_lds[tid]);
    if (tid >= 32 && tid < 64) atomicMax(&cmax_key[bc * NF + tid - 32], max_lds[tid - 32]);
    for (int i = tid; i < NW * 8; i += 256)
        atomicAdd(&colsum[bc * NW * 8 + i], col_lds[(i >> 3) * 9 + (i & 7)]);
}

// ---------------------------------------------------------------- precompute per-(bc): rowc[j][a], colc[j][w]
__global__ __launch_bounds__(256) void precomp_kernel(
    const float* __restrict__ rowsum, const float* __restrict__ colsum,
    const float* __restrict__ matsum, const unsigned* __restrict__ cmax_key,
    const float* __restrict__ w1, const float* __restrict__ b1,
    float* __restrict__ rowc, float* __restrict__ colc)
{
    __shared__ float sbm[NF];
    __shared__ float sconst[NHID];
    __shared__ float scs[NW * 8];
    int tid = threadIdx.x;
    int bc = blockIdx.x, b = bc / NC;

    for (int i = tid; i < NW * 8; i += 256) scs[i] = colsum[bc * NW * 8 + i];
    if (tid < NF) {
        unsigned km = cmax_key[(b * NC) * NF + tid];
        for (int c = 1; c < NC; c++) {
            unsigned kc = cmax_key[(b * NC + c) * NF + tid];
            km = (kc > km) ? kc : km;
        }
        sbm[tid] = funkey(km);
    }
    __syncthreads();
    if (tid < NHID) {
        float v = b1[tid];
        const float* mp = matsum + bc * 8;
        #pragma unroll
        for (int k = 0; k < 8; k++) v = fmaf(mp[k], w1[(24 + k) * NHID + tid], v);
        #pragma unroll
        for (int f = 0; f < NF; f++) v = fmaf(sbm[f], w1[(32 + f) * NHID + tid], v);
        sconst[tid] = v;
    }
    __syncthreads();
    for (int i = tid; i < NHID * NA; i += 256) {
        int j = i / NA, aa = i - j * NA;
        const float* rp = rowsum + (bc * NA + aa) * 8;
        float v = sconst[j];
        #pragma unroll
        for (int k = 0; k < 8; k++) v = fmaf(rp[k], w1[(8 + k) * NHID + j], v);
        rowc[(size_t)bc * (NHID * NA) + i] = v;
    }
    for (int i = tid; i < NHID * NW; i += 256) {
        int j = i / NW, ww = i - j * NW;
        float v = 0.f;
        #pragma unroll
        for (int k = 0; k < 8; k++) v = fmaf(scs[ww * 8 + k], w1[(16 + k) * NHID + j], v);
        colc[(size_t)bc * (NHID * NW) + i] = v;
    }
}

// ---------------------------------------------------------------- stack MLP (r12-proven, untouched): MFMA layer-2 + fused pools
__global__ __launch_bounds__(256, 4) void mlp_kernel(
    float* __restrict__ h, const float* __restrict__ rowc,
    const float* __restrict__ colc, const int* __restrict__ rows_len,
    const int* __restrict__ cols_len, const float* __restrict__ w1t,
    const unsigned short* __restrict__ w2bf, const float* __restrict__ b2,
    float* __restrict__ sqsum, float* __restrict__ rowsum,
    float* __restrict__ colsum, float* __restrict__ matsum,
    unsigned* __restrict__ cmax_key, int last, int do_pool)
{
    __shared__ unsigned int hid_hi[256 * HSTR];  // 17.4 KB
    __shared__ unsigned int hid_lo[256 * HSTR];  // 17.4 KB

    int tid = threadIdx.x;
    int bc = blockIdx.x / 36;
    int blk36 = blockIdx.x % 36;
    int base = blk36 * 256;
    int lane = tid & 63, wv = tid >> 6;
    int g = lane >> 4, c16 = lane & 15;

    int e = base + tid;
    int a = e / NW, wc = e - a * NW;
    float* hp = h + (size_t)bc * NF * AW;

    float p[8];
    #pragma unroll
    for (int k = 0; k < 8; k++) p[k] = __sinf(hp[(size_t)(4 * k) * AW + e]);
    v2f p2[4];
    #pragma unroll
    for (int t = 0; t < 4; t++) p2[t] = (v2f){p[2 * t], p[2 * t + 1]};

    const unsigned short* w2hi = w2bf;
    const unsigned short* w2lo = w2bf + NF * NHID;

    f32x4 acc[4][2];
    #pragma unroll
    for (int t = 0; t < 2; t++) {
        f32x4 bb = *(const f32x4*)(b2 + 16 * t + 4 * g);
        #pragma unroll
        for (int ti = 0; ti < 4; ti++) acc[ti][t] = bb;
    }

    const float* rcr = rowc + (size_t)bc * (NHID * NA);
    const float* rcc = colc + (size_t)bc * (NHID * NW);

    for (int w = 0; w < 4; w++) {
        int jw = 32 * w;
        frag_u Ah[2], Al[2];
        #pragma unroll
        for (int t = 0; t < 2; t++) {
            size_t off = (size_t)(c16 + 16 * t) * NHID + jw + 8 * g;
            const unsigned int* ph = (const unsigned int*)(w2hi + off);
            const unsigned int* pl = (const unsigned int*)(w2lo + off);
            #pragma unroll
            for (int d = 0; d < 4; d++) { Ah[t].u[d] = ph[d]; Al[t].u[d] = pl[d]; }
        }

        #pragma unroll 4
        for (int jp = 0; jp < 16; jp++) {
            int jl = 2 * jp;
            const v2f* w1r0 = (const v2f*)(w1t + (size_t)(jw + jl) * 24);
            const v2f* w1r1 = w1r0 + 12;
            v2f u0 = {rcr[(size_t)(jw + jl) * NA + a], rcc[(size_t)(jw + jl) * NW + wc]};
            v2f u1 = {rcr[(size_t)(jw + jl + 1) * NA + a], rcc[(size_t)(jw + jl + 1) * NW + wc]};
            #pragma unroll
            for (int t = 0; t < 4; t++) {
                u0 = PKFMA(p2[t], w1r0[t], u0);
                u1 = PKFMA(p2[t], w1r1[t], u1);
            }
            float v0 = fmaxf(u0.x + u0.y, 0.f);
            float v1 = fmaxf(u1.x + u1.y, 0.f);
            unsigned int hi, lo;
            asm("v_cvt_pk_bf16_f32 %0, %1, %2" : "=v"(hi) : "v"(v0), "v"(v1));
            float h0 = __uint_as_float(hi << 16);
            float h1 = __uint_as_float(hi & 0xffff0000u);
            float l0 = v0 - h0, l1 = v1 - h1;
            asm("v_cvt_pk_bf16_f32 %0, %1, %2" : "=v"(lo) : "v"(l0), "v"(l1));
            hid_hi[tid * HSTR + jp] = hi;
            hid_lo[tid * HSTR + jp] = lo;
        }
        __syncthreads();

        #pragma unroll
        for (int ti = 0; ti < 4; ti++) {
            int el = (wv * 4 + ti) * 16 + c16;
            const unsigned int* bh = &hid_hi[el * HSTR + 4 * g];
            const unsigned int* bl = &hid_lo[el * HSTR + 4 * g];
            frag_u Bh, Bl;
            #pragma unroll
            for (int d = 0; d < 4; d++) { Bh.u[d] = bh[d]; Bl.u[d] = bl[d]; }
            #pragma unroll
            for (int t = 0; t < 2; t++) {
                acc[ti][t] = __builtin_amdgcn_mfma_f32_16x16x32_bf16(Ah[t].s, Bh.s, acc[ti][t], 0, 0, 0);
                acc[ti][t] = __builtin_amdgcn_mfma_f32_16x16x32_bf16(Al[t].s, Bh.s, acc[ti][t], 0, 0, 0);
                acc[ti][t] = __builtin_amdgcn_mfma_f32_16x16x32_bf16(Ah[t].s, Bl.s, acc[ti][t], 0, 0, 0);
            }
        }
        __syncthreads();
    }

    // ---- pool LDS accumulators (alias dead hid_hi):
    float* col_lds = (float*)hid_hi;
    float* row_lds = col_lds + 96 * 9;
    float* mat_lds = row_lds + 32;
    unsigned* max_lds = (unsigned*)(mat_lds + 8);
    if (do_pool) {
        for (int i = tid; i < 96 * 9 + 32 + 8 + 32; i += 256) col_lds[i] = 0.f;
        __syncthreads();
    }

    int R = rows_len[bc], L = cols_len[bc];
    int a0 = base / NW;
    float psum[2][4] = {{0.f, 0.f, 0.f, 0.f}, {0.f, 0.f, 0.f, 0.f}};
    float matp[2] = {0.f, 0.f};
    float mxp[2][4];
    #pragma unroll
    for (int t = 0; t < 2; t++)
        #pragma unroll
        for (int r = 0; r < 4; r++) mxp[t][r] = -FLT_MAX;

    #pragma unroll
    for (int ti = 0; ti < 4; ti++) {
        int el = (wv * 4 + ti) * 16 + c16;
        int ee = base + el;
        int aa = ee / NW, ww = ee - aa * NW;
        float mk = (aa < R && ww < L) ? 1.f : 0.f;
        float rowv[2];
        #pragma unroll
        for (int t = 0; t < 2; t++) {
            #pragma unroll
            for (int r = 0; r < 4; r++) {
                int f = 4 * g + r + 16 * t;
                float* ad = hp + (size_t)f * AW + ee;
                float hv = (*ad + acc[ti][t][r]) * mk;
                if (!last) *ad = hv;
                else       psum[t][r] = fmaf(hv, hv, psum[t][r]);
                if (do_pool) {
                    mxp[t][r] = fmaxf(mxp[t][r], hv);
                    if (r == 1)      rowv[t] = __sinf(hv);
                    else if (r == 2) atomicAdd(&col_lds[ww * 9 + g + 4 * t], __sinf(hv));
                    else if (r == 3) matp[t] += __sinf(hv);
                }
            }
        }
        if (do_pool) {
            #pragma unroll
            for (int t = 0; t < 2; t++) {
                float v = grp16_sum(rowv[t]);
                if (c16 == 0) atomicAdd(&row_lds[(aa - a0) * 8 + g + 4 * t], v);
            }
        }
    }

    if (do_pool) {
        #pragma unroll
        for (int t = 0; t < 2; t++) {
            float v = grp16_sum(matp[t]);
            if (c16 == 0) atomicAdd(&mat_lds[g + 4 * t], v);
            #pragma unroll
            for (int r = 0; r < 4; r++) {
                float m = grp16_max(mxp[t][r]);
                if (c16 == 0) atomicMax(&max_lds[4 * g + r + 16 * t], fkey(m));
            }
        }
        __syncthreads();
        if (tid < 32) {
            int ar = a0 + (tid >> 3);
            if (ar < NA) atomicAdd(&rowsum[(bc * NA + ar) * 8 + (tid & 7)], row_lds[tid]);
        }
        if (tid < 8) atomicAdd(&matsum[bc * 8 + tid], mat_lds[tid]);
        if (tid >= 32 && tid < 64) atomicMax(&cmax_key[bc * NF + tid - 32], max_lds[tid - 32]);
        for (int i = tid; i < NW * 8; i += 256)
            atomicAdd(&colsum[bc * NW * 8 + i], col_lds[(i >> 3) * 9 + (i & 7)]);
    }

    if (last) {
        float* sq_lds = (float*)hid_hi;
        if (tid < NF) sq_lds[tid] = 0.f;
        __syncthreads();
        #pragma unroll
        for (int t = 0; t < 2; t++) {
            #pragma unroll
            for (int r = 0; r < 4; r++) {
                float v = grp16_sum(psum[t][r]);
                if (c16 == 0) atomicAdd(&sq_lds[4 * g + r + 16 * t], v);
            }
        }
        __syncthreads();
        if (tid < NF) atomicAdd(&sqsum[bc * NF + tid], sq_lds[tid]);
    }
}

// ---------------------------------------------------------------- final: rms from sqsum + mean-over-C + MLP + tanh
__global__ __launch_bounds__(64) void out_kernel(
    const float* __restrict__ sqsum, const int* __restrict__ rows_len,
    const int* __restrict__ cols_len, const float* __restrict__ w1,
    const float* __restrict__ b1, const float* __restrict__ w2,
    const float* __restrict__ b2, float* __restrict__ out)
{
    int b = threadIdx.x;
    if (b >= NB) return;
    float hm[NF];
    #pragma unroll
    for (int f = 0; f < NF; f++) hm[f] = 0.f;
    for (int c = 0; c < NC; c++) {
        int bc = b * NC + c;
        float n = (float)(rows_len[bc] * cols_len[bc]);
        float rdn = 1.f / fmaxf(n, 1e-12f);
        #pragma unroll
        for (int f = 0; f < NF; f++) {
            float q = fmaxf(sqsum[bc * NF + f], 1e-20f);
            hm[f] += sqrtf(q * rdn);
        }
    }
    #pragma unroll
    for (int f = 0; f < NF; f++) hm[f] *= (1.f / (float)NC);

    float o0 = b2[0], o1 = b2[1];
    for (int j = 0; j < NHID; j++) {
        float v = b1[j];
        #pragma unroll
        for (int f = 0; f < NF; f++) v = fmaf(hm[f], w1[f * NHID + j], v);
        v = fmaxf(v, 0.f);
        o0 = fmaf(v, w2[j * 2 + 0], o0);
        o1 = fmaf(v, w2[j * 2 + 1], o1);
    }
    out[b * 2 + 0] = 8.f * tanhf(o0);
    out[b * 2 + 1] = 8.f * tanhf(o1);
}

// ---------------------------------------------------------------- launcher
extern "C" void kernel_launch(void* const* d_in, const int* in_sizes, int n_in,
                              void* d_out, int out_size, void* d_ws, size_t ws_size,
                              hipStream_t stream)
{
    const float* x    = (const float*)d_in[0];
    const int* rl     = (const int*)d_in[1];
    const int* cl     = (const int*)d_in[2];
    const float* t0w1 = (const float*)d_in[3];
    const float* t0b1 = (const float*)d_in[4];
    const float* t0w2 = (const float*)d_in[5];
    const float* t0b2 = (const float*)d_in[6];
    const float* tw1  = (const float*)d_in[7];
    const float* tb1  = (const float*)d_in[8];
    const float* tw2  = (const float*)d_in[9];
    const float* tb2  = (const float*)d_in[10];
    const float* ow1  = (const float*)d_in[11];
    const float* ob1  = (const float*)d_in[12];
    const float* ow2  = (const float*)d_in[13];
    const float* ob2  = (const float*)d_in[14];
    float* out = (float*)d_out;

    float* ws    = (float*)d_ws;
    float* h     = ws;                               // NEL*NF
    float* stats = h + NEL * NF;                     // 2*NBC
    // --- contiguous accumulator region (single small memset per stack) ---
    float*    rowb = stats + 2 * NBC;                // NBC*NA*8 = 147456
    float*    matb = rowb + (size_t)NBC * NA * 8;    // NBC*8    = 1536
    unsigned* cmxb = (unsigned*)(matb + NBC * 8);    // NBC*NF   = 6144
    float*    colb = (float*)(cmxb + NBC * NF);      // NBC*NW*8 = 147456
    size_t    accum_floats = (size_t)NBC * NA * 8 + NBC * 8 + NBC * NF
                           + (size_t)NBC * NW * 8;   // 302592 floats = 1.2 MB
    // --- rest ---
    float* sqb   = colb + (size_t)NBC * NW * 8;      // NBC*NF
    float* w1tb  = sqb + NBC * NF;                   // 4*NHID*24
    float* rowcb = w1tb + 4 * NHID * 24;             // NBC*NHID*NA
    float* colcb = rowcb + (size_t)NBC * NHID * NA;  // NBC*NHID*NW
    unsigned short* w2bfb = (unsigned short*)(colcb + (size_t)NBC * NHID * NW);

    hipMemsetAsync(sqb, 0, NBC * NF * sizeof(float), stream);
    hipMemsetAsync(rowb, 0, accum_floats * sizeof(float), stream);  // for t0's fused pools
    stats_kernel<<<NBC, 256, 0, stream>>>(x, rl, cl, stats);
    prep_kernel<<<(4 * NHID * 24 + 255) / 256, 256, 0, stream>>>(tw1, w1tb);
    prep2_kernel<<<(4 * NF * NHID + 255) / 256, 256, 0, stream>>>(tw2, w2bfb);
    t0_kernel<<<(int)(NEL / 512), 256, 0, stream>>>(x, rl, cl, stats,
                                                    t0w1, t0b1, t0w2, t0b2, h,
                                                    rowb, colb, matb, cmxb);
    for (int s = 0; s < 4; s++) {
        precomp_kernel<<<NBC, 256, 0, stream>>>(rowb, colb, matb, cmxb,
            tw1 + (size_t)s * 64 * NHID, tb1 + s * NHID, rowcb, colcb);
        if (s < 3)
            hipMemsetAsync(rowb, 0, accum_floats * sizeof(float), stream);
        mlp_kernel<<<NBC * 36, 256, 0, stream>>>(h, rowcb, colcb, rl, cl,
            w1tb + (size_t)s * NHID * 24,
            w2bfb + (size_t)s * (2 * NF * NHID),
            tb2 + s * NF, sqb, rowb, colb, matb, cmxb,
            (s == 3) ? 1 : 0, (s < 3) ? 1 : 0);
    }
    out_kernel<<<1, 64, 0, stream>>>(sqb, rl, cl, ow1, ob1, ow2, ob2, out);
}

// Round 15
// 1337.312 us; speedup vs baseline: 1.3044x; 1.0218x over previous
//
#include <hip/hip_runtime.h>
#include <math.h>
#include <float.h>

#define NB 8
#define NC 24
#define NA 96
#define NW 96
#define NF 32
#define NHID 128
#define AW (NA*NW)           // 9216
#define NBC (NB*NC)          // 192
#define NEL ((size_t)NBC*AW) // 1769472
#define HSTR 17              // hid LDS row stride in dwords (v10-proven)

// packed fp32: <2 x float> fma -> v_pk_fma_f32 on gfx90a+/gfx950
typedef float v2f __attribute__((ext_vector_type(2)));
typedef float f32x4 __attribute__((ext_vector_type(4)));
typedef short short8_t __attribute__((ext_vector_type(8)));
#ifndef __has_builtin
#define __has_builtin(x) 0
#endif
#if __has_builtin(__builtin_elementwise_fma)
#define PKFMA(a,b,c) __builtin_elementwise_fma((a),(b),(c))
#else
#define PKFMA(a,b,c) ((a)*(b)+(c))
#endif

union frag_u { unsigned int u[4]; short8_t s; };

__device__ __forceinline__ unsigned short bf16rne(float x) {
    unsigned int u = __float_as_uint(x);
    unsigned int r = u + 0x7fffu + ((u >> 16) & 1u);
    return (unsigned short)(r >> 16);
}
__device__ __forceinline__ float bf2f(unsigned short v) {
    return __uint_as_float(((unsigned int)v) << 16);
}
// monotone float<->uint key (handles negatives); key(x1)<key(x2) iff x1<x2
__device__ __forceinline__ unsigned fkey(float x) {
    unsigned u = __float_as_uint(x);
    return (u >> 31) ? ~u : (u | 0x80000000u);
}
__device__ __forceinline__ float funkey(unsigned k) {
    return (k >> 31) ? __uint_as_float(k ^ 0x80000000u) : __uint_as_float(~k);
}
__device__ __forceinline__ float grp16_sum(float v) {
    v += __shfl_xor(v, 1, 64);
    v += __shfl_xor(v, 2, 64);
    v += __shfl_xor(v, 4, 64);
    v += __shfl_xor(v, 8, 64);
    return v;
}
__device__ __forceinline__ float grp16_max(float v) {
    v = fmaxf(v, __shfl_xor(v, 1, 64));
    v = fmaxf(v, __shfl_xor(v, 2, 64));
    v = fmaxf(v, __shfl_xor(v, 4, 64));
    v = fmaxf(v, __shfl_xor(v, 8, 64));
    return v;
}

// ---------------------------------------------------------------- stats
__global__ __launch_bounds__(256) void stats_kernel(
    const float* __restrict__ x, const int* __restrict__ rows_len,
    const int* __restrict__ cols_len, float* __restrict__ stats)
{
    int bc = blockIdx.x;
    int R = rows_len[bc], L = cols_len[bc];
    const float* xp = x + (size_t)bc * AW;
    int n = R * L;
    float sx = 0.f, sxx = 0.f;
    for (int i = threadIdx.x; i < n; i += 256) {
        int a = i / L, w = i - a * L;
        float v = xp[a * NW + w];
        sx += v;
        sxx = fmaf(v, v, sxx);
    }
    __shared__ float r1[256], r2[256];
    r1[threadIdx.x] = sx; r2[threadIdx.x] = sxx;
    __syncthreads();
    for (int s = 128; s > 0; s >>= 1) {
        if (threadIdx.x < s) {
            r1[threadIdx.x] += r1[threadIdx.x + s];
            r2[threadIdx.x] += r2[threadIdx.x + s];
        }
        __syncthreads();
    }
    if (threadIdx.x == 0) {
        float fn = (float)n;
        float mean = r1[0] / fn;
        float var = fmaxf((r2[0] - r1[0] * r1[0] / fn) / (fn - 1.f), 0.f);
        float sd = fmaxf(sqrtf(var), 1e-12f);
        stats[2 * bc] = mean;
        stats[2 * bc + 1] = 1.f / sd;
    }
}

// ---------------------------------------------------------------- prep: transpose first 24 rows of each stack's W1
__global__ __launch_bounds__(256) void prep_kernel(
    const float* __restrict__ tw1, float* __restrict__ w1t)
{
    int i = blockIdx.x * 256 + threadIdx.x;     // [s][j][t]
    if (i >= 4 * NHID * 24) return;
    int s = i / (NHID * 24), r = i % (NHID * 24);
    int j = r / 24, t = r % 24;
    w1t[i] = tw1[(size_t)s * 64 * NHID + t * NHID + j];
}

// ---------------------------------------------------------------- prep2: split W2^T into bf16 hi/lo (per stack)
__global__ __launch_bounds__(256) void prep2_kernel(
    const float* __restrict__ tw2, unsigned short* __restrict__ w2bf)
{
    int i = blockIdx.x * 256 + threadIdx.x;
    if (i >= 4 * NF * NHID) return;
    int s = i / (NF * NHID), r = i % (NF * NHID);
    int f = r / NHID, j = r % NHID;
    float v = tw2[((size_t)s * NHID + j) * NF + f];
    unsigned short hi = bf16rne(v);
    float hf = bf2f(hi);
    unsigned short lo = bf16rne(v - hf);
    size_t base = (size_t)s * (2 * NF * NHID) + (size_t)f * NHID + j;
    w2bf[base] = hi;
    w2bf[base + NF * NHID] = lo;
}

// ---------------------------------------------------------------- t0 MLP (1->128->32) + fused stack-0 pools; h stored bf16
__global__ __launch_bounds__(256, 4) void t0_kernel(
    const float* __restrict__ x, const int* __restrict__ rows_len,
    const int* __restrict__ cols_len, const float* __restrict__ stats,
    const float* __restrict__ w1, const float* __restrict__ b1,
    const float* __restrict__ w2, const float* __restrict__ b2,
    unsigned short* __restrict__ h, float* __restrict__ rowsum,
    float* __restrict__ colsum, float* __restrict__ matsum,
    unsigned* __restrict__ cmax_key)
{
    __shared__ float col_lds[96 * 9];   // stride 9 -> conflict-free atomics
    __shared__ float row_lds[8 * 8];    // 6 rows used
    __shared__ float mat_lds[8];
    __shared__ unsigned max_lds[NF];

    int tid = threadIdx.x;
    int bc = blockIdx.x / 18;
    int base = (blockIdx.x % 18) * 512;
    int lane = tid & 63, wv = tid >> 6;
    int c16 = lane & 15;
    int R = rows_len[bc], L = cols_len[bc];
    float mean = stats[2 * bc], rstd = stats[2 * bc + 1];

    for (int i = tid; i < 96 * 9; i += 256) col_lds[i] = 0.f;
    if (tid < 64) row_lds[tid] = 0.f;
    if (tid < 8) mat_lds[tid] = 0.f;
    if (tid < NF) max_lds[tid] = 0u;    // < fkey(x) for all finite x

    int eA = base + wv * 128 + lane;    // 16-aligned tiles, row-safe groups
    int eB = eA + 64;
    int aA = eA / NW, wA = eA % NW;
    int aB = eB / NW, wB = eB % NW;
    bool vA = (aA < R) && (wA < L);
    bool vB = (aB < R) && (wB < L);
    size_t gA = (size_t)bc * AW + eA;
    float xA = vA ? (x[gA] - mean) * rstd : 0.f;
    float xB = vB ? (x[gA + 64] - mean) * rstd : 0.f;

    v2f oA[16], oB[16];
    const v2f* b22 = (const v2f*)b2;
    #pragma unroll
    for (int i = 0; i < 16; i++) { v2f bb = b22[i]; oA[i] = bb; oB[i] = bb; }
    for (int j = 0; j < NHID; j++) {
        float hA = fmaxf(fmaf(xA, w1[j], b1[j]), 0.f);
        float hB = fmaxf(fmaf(xB, w1[j], b1[j]), 0.f);
        const v2f* wr = (const v2f*)&w2[j * NF];
        v2f hA2 = {hA, hA}, hB2 = {hB, hB};
        #pragma unroll
        for (int i = 0; i < 16; i++) {
            v2f q = wr[i];
            oA[i] = PKFMA(hA2, q, oA[i]);
            oB[i] = PKFMA(hB2, q, oB[i]);
        }
    }
    float mA = vA ? 1.f : 0.f, mB = vB ? 1.f : 0.f;
    unsigned short* hp = h + (size_t)bc * NF * AW;
    #pragma unroll
    for (int f = 0; f < NF; f++) {
        hp[(size_t)f * AW + eA] = bf16rne(oA[f >> 1][f & 1] * mA);
        hp[(size_t)f * AW + eB] = bf16rne(oB[f >> 1][f & 1] * mB);
    }
    __syncthreads();   // LDS accumulators zeroed

    // ---- fused stack-0 pools from in-register hv (pre-quantization fp32)
    int a0 = base / NW;
    int rowA = aA - a0, rowB = aB - a0;
    float matp[8];
    #pragma unroll
    for (int k = 0; k < 8; k++) matp[k] = 0.f;

    #pragma unroll
    for (int k = 0; k < 8; k++) {
        int fr = 4 * k + 1;
        float sA = grp16_sum(__sinf(oA[fr >> 1][fr & 1] * mA));
        float sB = grp16_sum(__sinf(oB[fr >> 1][fr & 1] * mB));
        if (c16 == 0) {
            atomicAdd(&row_lds[rowA * 8 + k], sA);
            atomicAdd(&row_lds[rowB * 8 + k], sB);
        }
        int fc = 4 * k + 2;
        atomicAdd(&col_lds[wA * 9 + k], __sinf(oA[fc >> 1][fc & 1] * mA));
        atomicAdd(&col_lds[wB * 9 + k], __sinf(oB[fc >> 1][fc & 1] * mB));
        int fm = 4 * k + 3;
        matp[k] = __sinf(oA[fm >> 1][fm & 1] * mA) + __sinf(oB[fm >> 1][fm & 1] * mB);
    }
    #pragma unroll
    for (int k = 0; k < 8; k++) {
        float v = grp16_sum(matp[k]);
        if (c16 == 0) atomicAdd(&mat_lds[k], v);
    }
    #pragma unroll
    for (int f = 0; f < NF; f++) {
        float v = grp16_max(fmaxf(oA[f >> 1][f & 1] * mA, oB[f >> 1][f & 1] * mB));
        if (c16 == 0) atomicMax(&max_lds[f], fkey(v));
    }
    __syncthreads();

    if (tid < 48) {
        int ar = a0 + (tid >> 3);
        if (ar < NA) atomicAdd(&rowsum[(bc * NA + ar) * 8 + (tid & 7)], row_lds[tid]);
    }
    if (tid < 8) atomicAdd(&matsum[bc * 8 + tid], mat_lds[tid]);
    if (tid >= 32 && tid < 64) atomicMax(&cmax_key[bc * NF + tid - 32], max_lds[tid - 32]);
    for (int i = tid; i < NW * 8; i += 256)
        atomicAdd(&colsum[bc * NW * 8 + i], col_lds[(i >> 3) * 9 + (i & 7)]);
}

// ---------------------------------------------------------------- precompute per-(bc): rowc[j][a], colc[j][w]
__global__ __launch_bounds__(256) void precomp_kernel(
    const float* __restrict__ rowsum, const float* __restrict__ colsum,
    const float* __restrict__ matsum, const unsigned* __restrict__ cmax_key,
    const float* __restrict__ w1, const float* __restrict__ b1,
    float* __restrict__ rowc, float* __restrict__ colc)
{
    __shared__ float sbm[NF];
    __shared__ float sconst[NHID];
    __shared__ float scs[NW * 8];
    int tid = threadIdx.x;
    int bc = blockIdx.x, b = bc / NC;

    for (int i = tid; i < NW * 8; i += 256) scs[i] = colsum[bc * NW * 8 + i];
    if (tid < NF) {
        unsigned km = cmax_key[(b * NC) * NF + tid];
        for (int c = 1; c < NC; c++) {
            unsigned kc = cmax_key[(b * NC + c) * NF + tid];
            km = (kc > km) ? kc : km;
        }
        sbm[tid] = funkey(km);
    }
    __syncthreads();
    if (tid < NHID) {
        float v = b1[tid];
        const float* mp = matsum + bc * 8;
        #pragma unroll
        for (int k = 0; k < 8; k++) v = fmaf(mp[k], w1[(24 + k) * NHID + tid], v);
        #pragma unroll
        for (int f = 0; f < NF; f++) v = fmaf(sbm[f], w1[(32 + f) * NHID + tid], v);
        sconst[tid] = v;
    }
    __syncthreads();
    for (int i = tid; i < NHID * NA; i += 256) {
        int j = i / NA, aa = i - j * NA;
        const float* rp = rowsum + (bc * NA + aa) * 8;
        float v = sconst[j];
        #pragma unroll
        for (int k = 0; k < 8; k++) v = fmaf(rp[k], w1[(8 + k) * NHID + j], v);
        rowc[(size_t)bc * (NHID * NA) + i] = v;
    }
    for (int i = tid; i < NHID * NW; i += 256) {
        int j = i / NW, ww = i - j * NW;
        float v = 0.f;
        #pragma unroll
        for (int k = 0; k < 8; k++) v = fmaf(scs[ww * 8 + k], w1[(16 + k) * NHID + j], v);
        colc[(size_t)bc * (NHID * NW) + i] = v;
    }
}

// ---------------------------------------------------------------- stack MLP: MFMA layer-2 + fused pools; h in bf16
__global__ __launch_bounds__(256, 4) void mlp_kernel(
    unsigned short* __restrict__ h, const float* __restrict__ rowc,
    const float* __restrict__ colc, const int* __restrict__ rows_len,
    const int* __restrict__ cols_len, const float* __restrict__ w1t,
    const unsigned short* __restrict__ w2bf, const float* __restrict__ b2,
    float* __restrict__ sqsum, float* __restrict__ rowsum,
    float* __restrict__ colsum, float* __restrict__ matsum,
    unsigned* __restrict__ cmax_key, int last, int do_pool)
{
    __shared__ unsigned int hid_hi[256 * HSTR];  // 17.4 KB
    __shared__ unsigned int hid_lo[256 * HSTR];  // 17.4 KB

    int tid = threadIdx.x;
    int bc = blockIdx.x / 36;
    int blk36 = blockIdx.x % 36;
    int base = blk36 * 256;
    int lane = tid & 63, wv = tid >> 6;
    int g = lane >> 4, c16 = lane & 15;

    int e = base + tid;
    int a = e / NW, wc = e - a * NW;
    unsigned short* hp = h + (size_t)bc * NF * AW;

    float p[8];
    #pragma unroll
    for (int k = 0; k < 8; k++) p[k] = __sinf(bf2f(hp[(size_t)(4 * k) * AW + e]));
    v2f p2[4];
    #pragma unroll
    for (int t = 0; t < 4; t++) p2[t] = (v2f){p[2 * t], p[2 * t + 1]};

    const unsigned short* w2hi = w2bf;
    const unsigned short* w2lo = w2bf + NF * NHID;

    f32x4 acc[4][2];
    #pragma unroll
    for (int t = 0; t < 2; t++) {
        f32x4 bb = *(const f32x4*)(b2 + 16 * t + 4 * g);
        #pragma unroll
        for (int ti = 0; ti < 4; ti++) acc[ti][t] = bb;
    }

    const float* rcr = rowc + (size_t)bc * (NHID * NA);
    const float* rcc = colc + (size_t)bc * (NHID * NW);

    for (int w = 0; w < 4; w++) {
        int jw = 32 * w;
        frag_u Ah[2], Al[2];
        #pragma unroll
        for (int t = 0; t < 2; t++) {
            size_t off = (size_t)(c16 + 16 * t) * NHID + jw + 8 * g;
            const unsigned int* ph = (const unsigned int*)(w2hi + off);
            const unsigned int* pl = (const unsigned int*)(w2lo + off);
            #pragma unroll
            for (int d = 0; d < 4; d++) { Ah[t].u[d] = ph[d]; Al[t].u[d] = pl[d]; }
        }

        #pragma unroll 4
        for (int jp = 0; jp < 16; jp++) {
            int jl = 2 * jp;
            const v2f* w1r0 = (const v2f*)(w1t + (size_t)(jw + jl) * 24);
            const v2f* w1r1 = w1r0 + 12;
            v2f u0 = {rcr[(size_t)(jw + jl) * NA + a], rcc[(size_t)(jw + jl) * NW + wc]};
            v2f u1 = {rcr[(size_t)(jw + jl + 1) * NA + a], rcc[(size_t)(jw + jl + 1) * NW + wc]};
            #pragma unroll
            for (int t = 0; t < 4; t++) {
                u0 = PKFMA(p2[t], w1r0[t], u0);
                u1 = PKFMA(p2[t], w1r1[t], u1);
            }
            float v0 = fmaxf(u0.x + u0.y, 0.f);
            float v1 = fmaxf(u1.x + u1.y, 0.f);
            unsigned int hi, lo;
            asm("v_cvt_pk_bf16_f32 %0, %1, %2" : "=v"(hi) : "v"(v0), "v"(v1));
            float h0 = __uint_as_float(hi << 16);
            float h1 = __uint_as_float(hi & 0xffff0000u);
            float l0 = v0 - h0, l1 = v1 - h1;
            asm("v_cvt_pk_bf16_f32 %0, %1, %2" : "=v"(lo) : "v"(l0), "v"(l1));
            hid_hi[tid * HSTR + jp] = hi;
            hid_lo[tid * HSTR + jp] = lo;
        }
        __syncthreads();

        #pragma unroll
        for (int ti = 0; ti < 4; ti++) {
            int el = (wv * 4 + ti) * 16 + c16;
            const unsigned int* bh = &hid_hi[el * HSTR + 4 * g];
            const unsigned int* bl = &hid_lo[el * HSTR + 4 * g];
            frag_u Bh, Bl;
            #pragma unroll
            for (int d = 0; d < 4; d++) { Bh.u[d] = bh[d]; Bl.u[d] = bl[d]; }
            #pragma unroll
            for (int t = 0; t < 2; t++) {
                acc[ti][t] = __builtin_amdgcn_mfma_f32_16x16x32_bf16(Ah[t].s, Bh.s, acc[ti][t], 0, 0, 0);
                acc[ti][t] = __builtin_amdgcn_mfma_f32_16x16x32_bf16(Al[t].s, Bh.s, acc[ti][t], 0, 0, 0);
                acc[ti][t] = __builtin_amdgcn_mfma_f32_16x16x32_bf16(Ah[t].s, Bl.s, acc[ti][t], 0, 0, 0);
            }
        }
        __syncthreads();
    }

    // ---- pool LDS accumulators (alias dead hid_hi):
    float* col_lds = (float*)hid_hi;
    float* row_lds = col_lds + 96 * 9;
    float* mat_lds = row_lds + 32;
    unsigned* max_lds = (unsigned*)(mat_lds + 8);
    if (do_pool) {
        for (int i = tid; i < 96 * 9 + 32 + 8 + 32; i += 256) col_lds[i] = 0.f;
        __syncthreads();
    }

    int R = rows_len[bc], L = cols_len[bc];
    int a0 = base / NW;
    float psum[2][4] = {{0.f, 0.f, 0.f, 0.f}, {0.f, 0.f, 0.f, 0.f}};
    float matp[2] = {0.f, 0.f};
    float mxp[2][4];
    #pragma unroll
    for (int t = 0; t < 2; t++)
        #pragma unroll
        for (int r = 0; r < 4; r++) mxp[t][r] = -FLT_MAX;

    #pragma unroll
    for (int ti = 0; ti < 4; ti++) {
        int el = (wv * 4 + ti) * 16 + c16;
        int ee = base + el;
        int aa = ee / NW, ww = ee - aa * NW;
        float mk = (aa < R && ww < L) ? 1.f : 0.f;
        float rowv[2];
        #pragma unroll
        for (int t = 0; t < 2; t++) {
            #pragma unroll
            for (int r = 0; r < 4; r++) {
                int f = 4 * g + r + 16 * t;
                unsigned short* ad = hp + (size_t)f * AW + ee;
                float hv = (bf2f(*ad) + acc[ti][t][r]) * mk;
                if (!last) *ad = bf16rne(hv);
                else       psum[t][r] = fmaf(hv, hv, psum[t][r]);
                if (do_pool) {
                    mxp[t][r] = fmaxf(mxp[t][r], hv);
                    if (r == 1)      rowv[t] = __sinf(hv);
                    else if (r == 2) atomicAdd(&col_lds[ww * 9 + g + 4 * t], __sinf(hv));
                    else if (r == 3) matp[t] += __sinf(hv);
                }
            }
        }
        if (do_pool) {
            #pragma unroll
            for (int t = 0; t < 2; t++) {
                float v = grp16_sum(rowv[t]);
                if (c16 == 0) atomicAdd(&row_lds[(aa - a0) * 8 + g + 4 * t], v);
            }
        }
    }

    if (do_pool) {
        #pragma unroll
        for (int t = 0; t < 2; t++) {
            float v = grp16_sum(matp[t]);
            if (c16 == 0) atomicAdd(&mat_lds[g + 4 * t], v);
            #pragma unroll
            for (int r = 0; r < 4; r++) {
                float m = grp16_max(mxp[t][r]);
                if (c16 == 0) atomicMax(&max_lds[4 * g + r + 16 * t], fkey(m));
            }
        }
        __syncthreads();
        if (tid < 32) {
            int ar = a0 + (tid >> 3);
            if (ar < NA) atomicAdd(&rowsum[(bc * NA + ar) * 8 + (tid & 7)], row_lds[tid]);
        }
        if (tid < 8) atomicAdd(&matsum[bc * 8 + tid], mat_lds[tid]);
        if (tid >= 32 && tid < 64) atomicMax(&cmax_key[bc * NF + tid - 32], max_lds[tid - 32]);
        for (int i = tid; i < NW * 8; i += 256)
            atomicAdd(&colsum[bc * NW * 8 + i], col_lds[(i >> 3) * 9 + (i & 7)]);
    }

    if (last) {
        float* sq_lds = (float*)hid_hi;
        if (tid < NF) sq_lds[tid] = 0.f;
        __syncthreads();
        #pragma unroll
        for (int t = 0; t < 2; t++) {
            #pragma unroll
            for (int r = 0; r < 4; r++) {
                float v = grp16_sum(psum[t][r]);
                if (c16 == 0) atomicAdd(&sq_lds[4 * g + r + 16 * t], v);
            }
        }
        __syncthreads();
        if (tid < NF) atomicAdd(&sqsum[bc * NF + tid], sq_lds[tid]);
    }
}

// ---------------------------------------------------------------- final: rms from sqsum + mean-over-C + MLP + tanh
__global__ __launch_bounds__(64) void out_kernel(
    const float* __restrict__ sqsum, const int* __restrict__ rows_len,
    const int* __restrict__ cols_len, const float* __restrict__ w1,
    const float* __restrict__ b1, const float* __restrict__ w2,
    const float* __restrict__ b2, float* __restrict__ out)
{
    int b = threadIdx.x;
    if (b >= NB) return;
    float hm[NF];
    #pragma unroll
    for (int f = 0; f < NF; f++) hm[f] = 0.f;
    for (int c = 0; c < NC; c++) {
        int bc = b * NC + c;
        float n = (float)(rows_len[bc] * cols_len[bc]);
        float rdn = 1.f / fmaxf(n, 1e-12f);
        #pragma unroll
        for (int f = 0; f < NF; f++) {
            float q = fmaxf(sqsum[bc * NF + f], 1e-20f);
            hm[f] += sqrtf(q * rdn);
        }
    }
    #pragma unroll
    for (int f = 0; f < NF; f++) hm[f] *= (1.f / (float)NC);

    float o0 = b2[0], o1 = b2[1];
    for (int j = 0; j < NHID; j++) {
        float v = b1[j];
        #pragma unroll
        for (int f = 0; f < NF; f++) v = fmaf(hm[f], w1[f * NHID + j], v);
        v = fmaxf(v, 0.f);
        o0 = fmaf(v, w2[j * 2 + 0], o0);
        o1 = fmaf(v, w2[j * 2 + 1], o1);
    }
    out[b * 2 + 0] = 8.f * tanhf(o0);
    out[b * 2 + 1] = 8.f * tanhf(o1);
}

// ---------------------------------------------------------------- launcher
extern "C" void kernel_launch(void* const* d_in, const int* in_sizes, int n_in,
                              void* d_out, int out_size, void* d_ws, size_t ws_size,
                              hipStream_t stream)
{
    const float* x    = (const float*)d_in[0];
    const int* rl     = (const int*)d_in[1];
    const int* cl     = (const int*)d_in[2];
    const float* t0w1 = (const float*)d_in[3];
    const float* t0b1 = (const float*)d_in[4];
    const float* t0w2 = (const float*)d_in[5];
    const float* t0b2 = (const float*)d_in[6];
    const float* tw1  = (const float*)d_in[7];
    const float* tb1  = (const float*)d_in[8];
    const float* tw2  = (const float*)d_in[9];
    const float* tb2  = (const float*)d_in[10];
    const float* ow1  = (const float*)d_in[11];
    const float* ob1  = (const float*)d_in[12];
    const float* ow2  = (const float*)d_in[13];
    const float* ob2  = (const float*)d_in[14];
    float* out = (float*)d_out;

    float* ws    = (float*)d_ws;
    unsigned short* h = (unsigned short*)ws;         // NEL*NF ushorts (region sized as floats; half used)
    float* stats = ws + NEL * NF;                    // 2*NBC
    // --- contiguous accumulator region (single small memset per stack) ---
    float*    rowb = stats + 2 * NBC;                // NBC*NA*8 = 147456
    float*    matb = rowb + (size_t)NBC * NA * 8;    // NBC*8    = 1536
    unsigned* cmxb = (unsigned*)(matb + NBC * 8);    // NBC*NF   = 6144
    float*    colb = (float*)(cmxb + NBC * NF);      // NBC*NW*8 = 147456
    size_t    accum_floats = (size_t)NBC * NA * 8 + NBC * 8 + NBC * NF
                           + (size_t)NBC * NW * 8;   // 302592 floats = 1.2 MB
    // --- rest ---
    float* sqb   = colb + (size_t)NBC * NW * 8;      // NBC*NF
    float* w1tb  = sqb + NBC * NF;                   // 4*NHID*24
    float* rowcb = w1tb + 4 * NHID * 24;             // NBC*NHID*NA
    float* colcb = rowcb + (size_t)NBC * NHID * NA;  // NBC*NHID*NW
    unsigned short* w2bfb = (unsigned short*)(colcb + (size_t)NBC * NHID * NW);

    hipMemsetAsync(sqb, 0, NBC * NF * sizeof(float), stream);
    hipMemsetAsync(rowb, 0, accum_floats * sizeof(float), stream);  // for t0's fused pools
    stats_kernel<<<NBC, 256, 0, stream>>>(x, rl, cl, stats);
    prep_kernel<<<(4 * NHID * 24 + 255) / 256, 256, 0, stream>>>(tw1, w1tb);
    prep2_kernel<<<(4 * NF * NHID + 255) / 256, 256, 0, stream>>>(tw2, w2bfb);
    t0_kernel<<<(int)(NEL / 512), 256, 0, stream>>>(x, rl, cl, stats,
                                                    t0w1, t0b1, t0w2, t0b2, h,
                                                    rowb, colb, matb, cmxb);
    for (int s = 0; s < 4; s++) {
        precomp_kernel<<<NBC, 256, 0, stream>>>(rowb, colb, matb, cmxb,
            tw1 + (size_t)s * 64 * NHID, tb1 + s * NHID, rowcb, colcb);
        if (s < 3)
            hipMemsetAsync(rowb, 0, accum_floats * sizeof(float), stream);
        mlp_kernel<<<NBC * 36, 256, 0, stream>>>(h, rowcb, colcb, rl, cl,
            w1tb + (size_t)s * NHID * 24,
            w2bfb + (size_t)s * (2 * NF * NHID),
            tb2 + s * NF, sqb, rowb, colb, matb, cmxb,
            (s == 3) ? 1 : 0, (s < 3) ? 1 : 0);
    }
    out_kernel<<<1, 64, 0, stream>>>(sqb, rl, cl, ow1, ob1, ow2, ob2, out);
}

// Round 16
// 1198.674 us; speedup vs baseline: 1.4553x; 1.1157x over previous
//
#include <hip/hip_runtime.h>
#include <math.h>
#include <float.h>

#define NB 8
#define NC 24
#define NA 96
#define NW 96
#define NF 32
#define NHID 128
#define AW (NA*NW)           // 9216
#define NBC (NB*NC)          // 192
#define NEL ((size_t)NBC*AW) // 1769472
#define HSTR 17              // hid LDS row stride in dwords (v10-proven)

// packed fp32: <2 x float> fma -> v_pk_fma_f32 on gfx90a+/gfx950
typedef float v2f __attribute__((ext_vector_type(2)));
typedef float f32x4 __attribute__((ext_vector_type(4)));
typedef short short8_t __attribute__((ext_vector_type(8)));
#ifndef __has_builtin
#define __has_builtin(x) 0
#endif
#if __has_builtin(__builtin_elementwise_fma)
#define PKFMA(a,b,c) __builtin_elementwise_fma((a),(b),(c))
#else
#define PKFMA(a,b,c) ((a)*(b)+(c))
#endif

union frag_u { unsigned int u[4]; short8_t s; };

__device__ __forceinline__ unsigned short bf16rne(float x) {
    unsigned int u = __float_as_uint(x);
    unsigned int r = u + 0x7fffu + ((u >> 16) & 1u);
    return (unsigned short)(r >> 16);
}
__device__ __forceinline__ float bf2f(unsigned short v) {
    return __uint_as_float(((unsigned int)v) << 16);
}
// monotone float<->uint key (handles negatives); key(x1)<key(x2) iff x1<x2
__device__ __forceinline__ unsigned fkey(float x) {
    unsigned u = __float_as_uint(x);
    return (u >> 31) ? ~u : (u | 0x80000000u);
}
__device__ __forceinline__ float funkey(unsigned k) {
    return (k >> 31) ? __uint_as_float(k ^ 0x80000000u) : __uint_as_float(~k);
}
__device__ __forceinline__ float grp16_sum(float v) {
    v += __shfl_xor(v, 1, 64);
    v += __shfl_xor(v, 2, 64);
    v += __shfl_xor(v, 4, 64);
    v += __shfl_xor(v, 8, 64);
    return v;
}
__device__ __forceinline__ float grp16_max(float v) {
    v = fmaxf(v, __shfl_xor(v, 1, 64));
    v = fmaxf(v, __shfl_xor(v, 2, 64));
    v = fmaxf(v, __shfl_xor(v, 4, 64));
    v = fmaxf(v, __shfl_xor(v, 8, 64));
    return v;
}
__device__ __forceinline__ void pack_hilo(float v0, float v1,
                                          unsigned int& hi, unsigned int& lo) {
    asm("v_cvt_pk_bf16_f32 %0, %1, %2" : "=v"(hi) : "v"(v0), "v"(v1));
    float h0 = __uint_as_float(hi << 16);
    float h1 = __uint_as_float(hi & 0xffff0000u);
    float l0 = v0 - h0, l1 = v1 - h1;
    asm("v_cvt_pk_bf16_f32 %0, %1, %2" : "=v"(lo) : "v"(l0), "v"(l1));
}

// ---------------------------------------------------------------- stats
__global__ __launch_bounds__(256) void stats_kernel(
    const float* __restrict__ x, const int* __restrict__ rows_len,
    const int* __restrict__ cols_len, float* __restrict__ stats)
{
    int bc = blockIdx.x;
    int R = rows_len[bc], L = cols_len[bc];
    const float* xp = x + (size_t)bc * AW;
    int n = R * L;
    float sx = 0.f, sxx = 0.f;
    for (int i = threadIdx.x; i < n; i += 256) {
        int a = i / L, w = i - a * L;
        float v = xp[a * NW + w];
        sx += v;
        sxx = fmaf(v, v, sxx);
    }
    __shared__ float r1[256], r2[256];
    r1[threadIdx.x] = sx; r2[threadIdx.x] = sxx;
    __syncthreads();
    for (int s = 128; s > 0; s >>= 1) {
        if (threadIdx.x < s) {
            r1[threadIdx.x] += r1[threadIdx.x + s];
            r2[threadIdx.x] += r2[threadIdx.x + s];
        }
        __syncthreads();
    }
    if (threadIdx.x == 0) {
        float fn = (float)n;
        float mean = r1[0] / fn;
        float var = fmaxf((r2[0] - r1[0] * r1[0] / fn) / (fn - 1.f), 0.f);
        float sd = fmaxf(sqrtf(var), 1e-12f);
        stats[2 * bc] = mean;
        stats[2 * bc + 1] = 1.f / sd;
    }
}

// ---------------------------------------------------------------- prep: transpose first 24 rows of each stack's W1
__global__ __launch_bounds__(256) void prep_kernel(
    const float* __restrict__ tw1, float* __restrict__ w1t)
{
    int i = blockIdx.x * 256 + threadIdx.x;     // [s][j][t]
    if (i >= 4 * NHID * 24) return;
    int s = i / (NHID * 24), r = i % (NHID * 24);
    int j = r / 24, t = r % 24;
    w1t[i] = tw1[(size_t)s * 64 * NHID + t * NHID + j];
}

// ---------------------------------------------------------------- prep2: split W2^T into bf16 hi/lo (per stack)
__global__ __launch_bounds__(256) void prep2_kernel(
    const float* __restrict__ tw2, unsigned short* __restrict__ w2bf)
{
    int i = blockIdx.x * 256 + threadIdx.x;
    if (i >= 4 * NF * NHID) return;
    int s = i / (NF * NHID), r = i % (NF * NHID);
    int f = r / NHID, j = r % NHID;
    float v = tw2[((size_t)s * NHID + j) * NF + f];
    unsigned short hi = bf16rne(v);
    unsigned short lo = bf16rne(v - bf2f(hi));
    size_t base = (size_t)s * (2 * NF * NHID) + (size_t)f * NHID + j;
    w2bf[base] = hi;
    w2bf[base + NF * NHID] = lo;
}

// ---------------------------------------------------------------- prep2t: split t0_w2 into bf16 hi/lo
__global__ __launch_bounds__(256) void prep2t_kernel(
    const float* __restrict__ t0w2, unsigned short* __restrict__ w2bf)
{
    int i = blockIdx.x * 256 + threadIdx.x;
    if (i >= NF * NHID) return;
    int f = i / NHID, j = i % NHID;
    float v = t0w2[(size_t)j * NF + f];
    unsigned short hi = bf16rne(v);
    unsigned short lo = bf16rne(v - bf2f(hi));
    w2bf[(size_t)f * NHID + j] = hi;
    w2bf[(size_t)NF * NHID + f * NHID + j] = lo;
}

// ---------------------------------------------------------------- t0 v3: MFMA layer-2 (mlp template) + fused stack-0 pools
// Phase A: hidden = relu(xn*w1[j]+b1[j]) (scalar x, no seed loads) -> bf16
// hi/lo -> LDS. Phase B + pool epilogue copied from the proven mlp kernel.
// No residual read (h fresh); h written bf16.
__global__ __launch_bounds__(256, 4) void t0_kernel(
    const float* __restrict__ x, const int* __restrict__ rows_len,
    const int* __restrict__ cols_len, const float* __restrict__ stats,
    const float* __restrict__ w1, const float* __restrict__ b1,
    const unsigned short* __restrict__ w2bf, const float* __restrict__ b2,
    unsigned short* __restrict__ h, float* __restrict__ rowsum,
    float* __restrict__ colsum, float* __restrict__ matsum,
    unsigned* __restrict__ cmax_key)
{
    __shared__ unsigned int hid_hi[256 * HSTR];
    __shared__ unsigned int hid_lo[256 * HSTR];

    int tid = threadIdx.x;
    int bc = blockIdx.x / 36;
    int blk36 = blockIdx.x % 36;
    int base = blk36 * 256;
    int lane = tid & 63, wv = tid >> 6;
    int g = lane >> 4, c16 = lane & 15;

    int e = base + tid;
    int a = e / NW, wc = e - a * NW;
    int R = rows_len[bc], L = cols_len[bc];
    float mean = stats[2 * bc], rstd = stats[2 * bc + 1];
    bool valid = (a < R) && (wc < L);
    float xn = valid ? (x[(size_t)bc * AW + e] - mean) * rstd : 0.f;
    unsigned short* hp = h + (size_t)bc * NF * AW;

    const unsigned short* w2hi = w2bf;
    const unsigned short* w2lo = w2bf + NF * NHID;

    f32x4 acc[4][2];
    #pragma unroll
    for (int t = 0; t < 2; t++) {
        f32x4 bb = *(const f32x4*)(b2 + 16 * t + 4 * g);
        #pragma unroll
        for (int ti = 0; ti < 4; ti++) acc[ti][t] = bb;
    }

    for (int w = 0; w < 4; w++) {
        int jw = 32 * w;
        frag_u Ah[2], Al[2];
        #pragma unroll
        for (int t = 0; t < 2; t++) {
            size_t off = (size_t)(c16 + 16 * t) * NHID + jw + 8 * g;
            const unsigned int* ph = (const unsigned int*)(w2hi + off);
            const unsigned int* pl = (const unsigned int*)(w2lo + off);
            #pragma unroll
            for (int d = 0; d < 4; d++) { Ah[t].u[d] = ph[d]; Al[t].u[d] = pl[d]; }
        }

        #pragma unroll 4
        for (int jp = 0; jp < 16; jp++) {
            int j0 = jw + 2 * jp;
            float v0 = fmaxf(fmaf(xn, w1[j0], b1[j0]), 0.f);
            float v1 = fmaxf(fmaf(xn, w1[j0 + 1], b1[j0 + 1]), 0.f);
            unsigned int hi, lo;
            pack_hilo(v0, v1, hi, lo);
            hid_hi[tid * HSTR + jp] = hi;
            hid_lo[tid * HSTR + jp] = lo;
        }
        __syncthreads();

        #pragma unroll
        for (int ti = 0; ti < 4; ti++) {
            int el = (wv * 4 + ti) * 16 + c16;
            const unsigned int* bh = &hid_hi[el * HSTR + 4 * g];
            const unsigned int* bl = &hid_lo[el * HSTR + 4 * g];
            frag_u Bh, Bl;
            #pragma unroll
            for (int d = 0; d < 4; d++) { Bh.u[d] = bh[d]; Bl.u[d] = bl[d]; }
            #pragma unroll
            for (int t = 0; t < 2; t++) {
                acc[ti][t] = __builtin_amdgcn_mfma_f32_16x16x32_bf16(Ah[t].s, Bh.s, acc[ti][t], 0, 0, 0);
                acc[ti][t] = __builtin_amdgcn_mfma_f32_16x16x32_bf16(Al[t].s, Bh.s, acc[ti][t], 0, 0, 0);
                acc[ti][t] = __builtin_amdgcn_mfma_f32_16x16x32_bf16(Ah[t].s, Bl.s, acc[ti][t], 0, 0, 0);
            }
        }
        __syncthreads();
    }

    // ---- pool LDS accumulators (alias dead hid_hi)
    float* col_lds = (float*)hid_hi;
    float* row_lds = col_lds + 96 * 9;
    float* mat_lds = row_lds + 32;
    unsigned* max_lds = (unsigned*)(mat_lds + 8);
    for (int i = tid; i < 96 * 9 + 32 + 8 + 32; i += 256) col_lds[i] = 0.f;
    __syncthreads();

    int a0 = base / NW;
    float matp[2] = {0.f, 0.f};
    float mxp[2][4];
    #pragma unroll
    for (int t = 0; t < 2; t++)
        #pragma unroll
        for (int r = 0; r < 4; r++) mxp[t][r] = -FLT_MAX;

    #pragma unroll
    for (int ti = 0; ti < 4; ti++) {
        int el = (wv * 4 + ti) * 16 + c16;
        int ee = base + el;
        int aa = ee / NW, ww = ee - aa * NW;
        float mk = (aa < R && ww < L) ? 1.f : 0.f;
        float rowv[2];
        #pragma unroll
        for (int t = 0; t < 2; t++) {
            #pragma unroll
            for (int r = 0; r < 4; r++) {
                int f = 4 * g + r + 16 * t;
                float hv = acc[ti][t][r] * mk;
                hp[(size_t)f * AW + ee] = bf16rne(hv);
                mxp[t][r] = fmaxf(mxp[t][r], hv);
                if (r == 1)      rowv[t] = __sinf(hv);
                else if (r == 2) atomicAdd(&col_lds[ww * 9 + g + 4 * t], __sinf(hv));
                else if (r == 3) matp[t] += __sinf(hv);
            }
        }
        #pragma unroll
        for (int t = 0; t < 2; t++) {
            float v = grp16_sum(rowv[t]);
            if (c16 == 0) atomicAdd(&row_lds[(aa - a0) * 8 + g + 4 * t], v);
        }
    }

    #pragma unroll
    for (int t = 0; t < 2; t++) {
        float v = grp16_sum(matp[t]);
        if (c16 == 0) atomicAdd(&mat_lds[g + 4 * t], v);
        #pragma unroll
        for (int r = 0; r < 4; r++) {
            float m = grp16_max(mxp[t][r]);
            if (c16 == 0) atomicMax(&max_lds[4 * g + r + 16 * t], fkey(m));
        }
    }
    __syncthreads();
    if (tid < 32) {
        int ar = a0 + (tid >> 3);
        if (ar < NA) atomicAdd(&rowsum[(bc * NA + ar) * 8 + (tid & 7)], row_lds[tid]);
    }
    if (tid < 8) atomicAdd(&matsum[bc * 8 + tid], mat_lds[tid]);
    if (tid >= 32 && tid < 64) atomicMax(&cmax_key[bc * NF + tid - 32], max_lds[tid - 32]);
    for (int i = tid; i < NW * 8; i += 256)
        atomicAdd(&colsum[bc * NW * 8 + i], col_lds[(i >> 3) * 9 + (i & 7)]);
}

// ---------------------------------------------------------------- precompute per-(bc): rowc[j][a], colc[j][w]
__global__ __launch_bounds__(256) void precomp_kernel(
    const float* __restrict__ rowsum, const float* __restrict__ colsum,
    const float* __restrict__ matsum, const unsigned* __restrict__ cmax_key,
    const float* __restrict__ w1, const float* __restrict__ b1,
    float* __restrict__ rowc, float* __restrict__ colc)
{
    __shared__ float sbm[NF];
    __shared__ float sconst[NHID];
    __shared__ float scs[NW * 8];
    int tid = threadIdx.x;
    int bc = blockIdx.x, b = bc / NC;

    for (int i = tid; i < NW * 8; i += 256) scs[i] = colsum[bc * NW * 8 + i];
    if (tid < NF) {
        unsigned km = cmax_key[(b * NC) * NF + tid];
        for (int c = 1; c < NC; c++) {
            unsigned kc = cmax_key[(b * NC + c) * NF + tid];
            km = (kc > km) ? kc : km;
        }
        sbm[tid] = funkey(km);
    }
    __syncthreads();
    if (tid < NHID) {
        float v = b1[tid];
        const float* mp = matsum + bc * 8;
        #pragma unroll
        for (int k = 0; k < 8; k++) v = fmaf(mp[k], w1[(24 + k) * NHID + tid], v);
        #pragma unroll
        for (int f = 0; f < NF; f++) v = fmaf(sbm[f], w1[(32 + f) * NHID + tid], v);
        sconst[tid] = v;
    }
    __syncthreads();
    for (int i = tid; i < NHID * NA; i += 256) {
        int j = i / NA, aa = i - j * NA;
        const float* rp = rowsum + (bc * NA + aa) * 8;
        float v = sconst[j];
        #pragma unroll
        for (int k = 0; k < 8; k++) v = fmaf(rp[k], w1[(8 + k) * NHID + j], v);
        rowc[(size_t)bc * (NHID * NA) + i] = v;
    }
    for (int i = tid; i < NHID * NW; i += 256) {
        int j = i / NW, ww = i - j * NW;
        float v = 0.f;
        #pragma unroll
        for (int k = 0; k < 8; k++) v = fmaf(scs[ww * 8 + k], w1[(16 + k) * NHID + j], v);
        colc[(size_t)bc * (NHID * NW) + i] = v;
    }
}

// ---------------------------------------------------------------- shared mlp core (phases A+B), returns acc
__device__ __forceinline__ void mlp_core(
    int tid, int bc, int base, int a, int wc, int g, int c16, int wv,
    const unsigned short* hp, const float* rcr, const float* rcc,
    const float* __restrict__ w1t, const unsigned short* __restrict__ w2bf,
    const float* __restrict__ b2, unsigned int* hid_hi, unsigned int* hid_lo,
    f32x4 (&acc)[4][2])
{
    int e = base + tid;
    float p[8];
    #pragma unroll
    for (int k = 0; k < 8; k++) p[k] = __sinf(bf2f(hp[(size_t)(4 * k) * AW + e]));
    v2f p2[4];
    #pragma unroll
    for (int t = 0; t < 4; t++) p2[t] = (v2f){p[2 * t], p[2 * t + 1]};

    const unsigned short* w2hi = w2bf;
    const unsigned short* w2lo = w2bf + NF * NHID;

    #pragma unroll
    for (int t = 0; t < 2; t++) {
        f32x4 bb = *(const f32x4*)(b2 + 16 * t + 4 * g);
        #pragma unroll
        for (int ti = 0; ti < 4; ti++) acc[ti][t] = bb;
    }

    for (int w = 0; w < 4; w++) {
        int jw = 32 * w;
        frag_u Ah[2], Al[2];
        #pragma unroll
        for (int t = 0; t < 2; t++) {
            size_t off = (size_t)(c16 + 16 * t) * NHID + jw + 8 * g;
            const unsigned int* ph = (const unsigned int*)(w2hi + off);
            const unsigned int* pl = (const unsigned int*)(w2lo + off);
            #pragma unroll
            for (int d = 0; d < 4; d++) { Ah[t].u[d] = ph[d]; Al[t].u[d] = pl[d]; }
        }

        #pragma unroll 4
        for (int jp = 0; jp < 16; jp++) {
            int jl = 2 * jp;
            const v2f* w1r0 = (const v2f*)(w1t + (size_t)(jw + jl) * 24);
            const v2f* w1r1 = w1r0 + 12;
            v2f u0 = {rcr[(size_t)(jw + jl) * NA + a], rcc[(size_t)(jw + jl) * NW + wc]};
            v2f u1 = {rcr[(size_t)(jw + jl + 1) * NA + a], rcc[(size_t)(jw + jl + 1) * NW + wc]};
            #pragma unroll
            for (int t = 0; t < 4; t++) {
                u0 = PKFMA(p2[t], w1r0[t], u0);
                u1 = PKFMA(p2[t], w1r1[t], u1);
            }
            float v0 = fmaxf(u0.x + u0.y, 0.f);
            float v1 = fmaxf(u1.x + u1.y, 0.f);
            unsigned int hi, lo;
            pack_hilo(v0, v1, hi, lo);
            hid_hi[tid * HSTR + jp] = hi;
            hid_lo[tid * HSTR + jp] = lo;
        }
        __syncthreads();

        #pragma unroll
        for (int ti = 0; ti < 4; ti++) {
            int el = (wv * 4 + ti) * 16 + c16;
            const unsigned int* bh = &hid_hi[el * HSTR + 4 * g];
            const unsigned int* bl = &hid_lo[el * HSTR + 4 * g];
            frag_u Bh, Bl;
            #pragma unroll
            for (int d = 0; d < 4; d++) { Bh.u[d] = bh[d]; Bl.u[d] = bl[d]; }
            #pragma unroll
            for (int t = 0; t < 2; t++) {
                acc[ti][t] = __builtin_amdgcn_mfma_f32_16x16x32_bf16(Ah[t].s, Bh.s, acc[ti][t], 0, 0, 0);
                acc[ti][t] = __builtin_amdgcn_mfma_f32_16x16x32_bf16(Al[t].s, Bh.s, acc[ti][t], 0, 0, 0);
                acc[ti][t] = __builtin_amdgcn_mfma_f32_16x16x32_bf16(Ah[t].s, Bl.s, acc[ti][t], 0, 0, 0);
            }
        }
        __syncthreads();
    }
}

// ---------------------------------------------------------------- mlp_mid: stacks 0..2 — write h + fused pools
__global__ __launch_bounds__(256, 4) void mlp_mid_kernel(
    unsigned short* __restrict__ h, const float* __restrict__ rowc,
    const float* __restrict__ colc, const int* __restrict__ rows_len,
    const int* __restrict__ cols_len, const float* __restrict__ w1t,
    const unsigned short* __restrict__ w2bf, const float* __restrict__ b2,
    float* __restrict__ rowsum, float* __restrict__ colsum,
    float* __restrict__ matsum, unsigned* __restrict__ cmax_key)
{
    __shared__ unsigned int hid_hi[256 * HSTR];
    __shared__ unsigned int hid_lo[256 * HSTR];

    int tid = threadIdx.x;
    int bc = blockIdx.x / 36;
    int blk36 = blockIdx.x % 36;
    int base = blk36 * 256;
    int lane = tid & 63, wv = tid >> 6;
    int g = lane >> 4, c16 = lane & 15;
    int e = base + tid;
    int a = e / NW, wc = e - a * NW;
    unsigned short* hp = h + (size_t)bc * NF * AW;
    const float* rcr = rowc + (size_t)bc * (NHID * NA);
    const float* rcc = colc + (size_t)bc * (NHID * NW);

    f32x4 acc[4][2];
    mlp_core(tid, bc, base, a, wc, g, c16, wv, hp, rcr, rcc, w1t, w2bf, b2,
             hid_hi, hid_lo, acc);

    float* col_lds = (float*)hid_hi;
    float* row_lds = col_lds + 96 * 9;
    float* mat_lds = row_lds + 32;
    unsigned* max_lds = (unsigned*)(mat_lds + 8);
    for (int i = tid; i < 96 * 9 + 32 + 8 + 32; i += 256) col_lds[i] = 0.f;
    __syncthreads();

    int R = rows_len[bc], L = cols_len[bc];
    int a0 = base / NW;
    float matp[2] = {0.f, 0.f};
    float mxp[2][4];
    #pragma unroll
    for (int t = 0; t < 2; t++)
        #pragma unroll
        for (int r = 0; r < 4; r++) mxp[t][r] = -FLT_MAX;

    #pragma unroll
    for (int ti = 0; ti < 4; ti++) {
        int el = (wv * 4 + ti) * 16 + c16;
        int ee = base + el;
        int aa = ee / NW, ww = ee - aa * NW;
        float mk = (aa < R && ww < L) ? 1.f : 0.f;
        float rowv[2];
        #pragma unroll
        for (int t = 0; t < 2; t++) {
            #pragma unroll
            for (int r = 0; r < 4; r++) {
                int f = 4 * g + r + 16 * t;
                unsigned short* ad = hp + (size_t)f * AW + ee;
                float hv = (bf2f(*ad) + acc[ti][t][r]) * mk;
                *ad = bf16rne(hv);
                mxp[t][r] = fmaxf(mxp[t][r], hv);
                if (r == 1)      rowv[t] = __sinf(hv);
                else if (r == 2) atomicAdd(&col_lds[ww * 9 + g + 4 * t], __sinf(hv));
                else if (r == 3) matp[t] += __sinf(hv);
            }
        }
        #pragma unroll
        for (int t = 0; t < 2; t++) {
            float v = grp16_sum(rowv[t]);
            if (c16 == 0) atomicAdd(&row_lds[(aa - a0) * 8 + g + 4 * t], v);
        }
    }

    #pragma unroll
    for (int t = 0; t < 2; t++) {
        float v = grp16_sum(matp[t]);
        if (c16 == 0) atomicAdd(&mat_lds[g + 4 * t], v);
        #pragma unroll
        for (int r = 0; r < 4; r++) {
            float m = grp16_max(mxp[t][r]);
            if (c16 == 0) atomicMax(&max_lds[4 * g + r + 16 * t], fkey(m));
        }
    }
    __syncthreads();
    if (tid < 32) {
        int ar = a0 + (tid >> 3);
        if (ar < NA) atomicAdd(&rowsum[(bc * NA + ar) * 8 + (tid & 7)], row_lds[tid]);
    }
    if (tid < 8) atomicAdd(&matsum[bc * 8 + tid], mat_lds[tid]);
    if (tid >= 32 && tid < 64) atomicMax(&cmax_key[bc * NF + tid - 32], max_lds[tid - 32]);
    for (int i = tid; i < NW * 8; i += 256)
        atomicAdd(&colsum[bc * NW * 8 + i], col_lds[(i >> 3) * 9 + (i & 7)]);
}

// ---------------------------------------------------------------- mlp_last: stack 3 — sqsum only, no h write
__global__ __launch_bounds__(256, 4) void mlp_last_kernel(
    unsigned short* __restrict__ h, const float* __restrict__ rowc,
    const float* __restrict__ colc, const int* __restrict__ rows_len,
    const int* __restrict__ cols_len, const float* __restrict__ w1t,
    const unsigned short* __restrict__ w2bf, const float* __restrict__ b2,
    float* __restrict__ sqsum)
{
    __shared__ unsigned int hid_hi[256 * HSTR];
    __shared__ unsigned int hid_lo[256 * HSTR];

    int tid = threadIdx.x;
    int bc = blockIdx.x / 36;
    int blk36 = blockIdx.x % 36;
    int base = blk36 * 256;
    int lane = tid & 63, wv = tid >> 6;
    int g = lane >> 4, c16 = lane & 15;
    int e = base + tid;
    int a = e / NW, wc = e - a * NW;
    unsigned short* hp = h + (size_t)bc * NF * AW;
    const float* rcr = rowc + (size_t)bc * (NHID * NA);
    const float* rcc = colc + (size_t)bc * (NHID * NW);

    f32x4 acc[4][2];
    mlp_core(tid, bc, base, a, wc, g, c16, wv, hp, rcr, rcc, w1t, w2bf, b2,
             hid_hi, hid_lo, acc);

    int R = rows_len[bc], L = cols_len[bc];
    float psum[2][4] = {{0.f, 0.f, 0.f, 0.f}, {0.f, 0.f, 0.f, 0.f}};
    #pragma unroll
    for (int ti = 0; ti < 4; ti++) {
        int el = (wv * 4 + ti) * 16 + c16;
        int ee = base + el;
        int aa = ee / NW, ww = ee - aa * NW;
        float mk = (aa < R && ww < L) ? 1.f : 0.f;
        #pragma unroll
        for (int t = 0; t < 2; t++) {
            #pragma unroll
            for (int r = 0; r < 4; r++) {
                int f = 4 * g + r + 16 * t;
                float hv = (bf2f(hp[(size_t)f * AW + ee]) + acc[ti][t][r]) * mk;
                psum[t][r] = fmaf(hv, hv, psum[t][r]);
            }
        }
    }
    float* sq_lds = (float*)hid_hi;
    if (tid < NF) sq_lds[tid] = 0.f;
    __syncthreads();
    #pragma unroll
    for (int t = 0; t < 2; t++) {
        #pragma unroll
        for (int r = 0; r < 4; r++) {
            float v = grp16_sum(psum[t][r]);
            if (c16 == 0) atomicAdd(&sq_lds[4 * g + r + 16 * t], v);
        }
    }
    __syncthreads();
    if (tid < NF) atomicAdd(&sqsum[bc * NF + tid], sq_lds[tid]);
}

// ---------------------------------------------------------------- final: rms from sqsum + mean-over-C + MLP + tanh
__global__ __launch_bounds__(64) void out_kernel(
    const float* __restrict__ sqsum, const int* __restrict__ rows_len,
    const int* __restrict__ cols_len, const float* __restrict__ w1,
    const float* __restrict__ b1, const float* __restrict__ w2,
    const float* __restrict__ b2, float* __restrict__ out)
{
    int b = threadIdx.x;
    if (b >= NB) return;
    float hm[NF];
    #pragma unroll
    for (int f = 0; f < NF; f++) hm[f] = 0.f;
    for (int c = 0; c < NC; c++) {
        int bc = b * NC + c;
        float n = (float)(rows_len[bc] * cols_len[bc]);
        float rdn = 1.f / fmaxf(n, 1e-12f);
        #pragma unroll
        for (int f = 0; f < NF; f++) {
            float q = fmaxf(sqsum[bc * NF + f], 1e-20f);
            hm[f] += sqrtf(q * rdn);
        }
    }
    #pragma unroll
    for (int f = 0; f < NF; f++) hm[f] *= (1.f / (float)NC);

    float o0 = b2[0], o1 = b2[1];
    for (int j = 0; j < NHID; j++) {
        float v = b1[j];
        #pragma unroll
        for (int f = 0; f < NF; f++) v = fmaf(hm[f], w1[f * NHID + j], v);
        v = fmaxf(v, 0.f);
        o0 = fmaf(v, w2[j * 2 + 0], o0);
        o1 = fmaf(v, w2[j * 2 + 1], o1);
    }
    out[b * 2 + 0] = 8.f * tanhf(o0);
    out[b * 2 + 1] = 8.f * tanhf(o1);
}

// ---------------------------------------------------------------- launcher
extern "C" void kernel_launch(void* const* d_in, const int* in_sizes, int n_in,
                              void* d_out, int out_size, void* d_ws, size_t ws_size,
                              hipStream_t stream)
{
    const float* x    = (const float*)d_in[0];
    const int* rl     = (const int*)d_in[1];
    const int* cl     = (const int*)d_in[2];
    const float* t0w1 = (const float*)d_in[3];
    const float* t0b1 = (const float*)d_in[4];
    const float* t0w2 = (const float*)d_in[5];
    const float* t0b2 = (const float*)d_in[6];
    const float* tw1  = (const float*)d_in[7];
    const float* tb1  = (const float*)d_in[8];
    const float* tw2  = (const float*)d_in[9];
    const float* tb2  = (const float*)d_in[10];
    const float* ow1  = (const float*)d_in[11];
    const float* ob1  = (const float*)d_in[12];
    const float* ow2  = (const float*)d_in[13];
    const float* ob2  = (const float*)d_in[14];
    float* out = (float*)d_out;

    float* ws    = (float*)d_ws;
    unsigned short* h = (unsigned short*)ws;         // NEL*NF ushorts (region sized as floats; half used)
    float* stats = ws + NEL * NF;                    // 2*NBC
    // --- contiguous accumulator region (single small memset per stack) ---
    float*    rowb = stats + 2 * NBC;                // NBC*NA*8 = 147456
    float*    matb = rowb + (size_t)NBC * NA * 8;    // NBC*8    = 1536
    unsigned* cmxb = (unsigned*)(matb + NBC * 8);    // NBC*NF   = 6144
    float*    colb = (float*)(cmxb + NBC * NF);      // NBC*NW*8 = 147456
    size_t    accum_floats = (size_t)NBC * NA * 8 + NBC * 8 + NBC * NF
                           + (size_t)NBC * NW * 8;   // 302592 floats = 1.2 MB
    // --- rest ---
    float* sqb   = colb + (size_t)NBC * NW * 8;      // NBC*NF
    float* w1tb  = sqb + NBC * NF;                   // 4*NHID*24
    float* rowcb = w1tb + 4 * NHID * 24;             // NBC*NHID*NA
    float* colcb = rowcb + (size_t)NBC * NHID * NA;  // NBC*NHID*NW
    unsigned short* w2bfb = (unsigned short*)(colcb + (size_t)NBC * NHID * NW); // 4*2*NF*NHID
    unsigned short* w2t0b = w2bfb + (size_t)4 * 2 * NF * NHID;                  // 2*NF*NHID

    hipMemsetAsync(sqb, 0, NBC * NF * sizeof(float), stream);
    hipMemsetAsync(rowb, 0, accum_floats * sizeof(float), stream);  // for t0's fused pools
    stats_kernel<<<NBC, 256, 0, stream>>>(x, rl, cl, stats);
    prep_kernel<<<(4 * NHID * 24 + 255) / 256, 256, 0, stream>>>(tw1, w1tb);
    prep2_kernel<<<(4 * NF * NHID + 255) / 256, 256, 0, stream>>>(tw2, w2bfb);
    prep2t_kernel<<<(NF * NHID + 255) / 256, 256, 0, stream>>>(t0w2, w2t0b);
    t0_kernel<<<NBC * 36, 256, 0, stream>>>(x, rl, cl, stats,
                                            t0w1, t0b1, w2t0b, t0b2, h,
                                            rowb, colb, matb, cmxb);
    for (int s = 0; s < 4; s++) {
        precomp_kernel<<<NBC, 256, 0, stream>>>(rowb, colb, matb, cmxb,
            tw1 + (size_t)s * 64 * NHID, tb1 + s * NHID, rowcb, colcb);
        if (s < 3) {
            hipMemsetAsync(rowb, 0, accum_floats * sizeof(float), stream);
            mlp_mid_kernel<<<NBC * 36, 256, 0, stream>>>(h, rowcb, colcb, rl, cl,
                w1tb + (size_t)s * NHID * 24,
                w2bfb + (size_t)s * (2 * NF * NHID),
                tb2 + s * NF, rowb, colb, matb, cmxb);
        } else {
            mlp_last_kernel<<<NBC * 36, 256, 0, stream>>>(h, rowcb, colcb, rl, cl,
                w1tb + (size_t)s * NHID * 24,
                w2bfb + (size_t)s * (2 * NF * NHID),
                tb2 + s * NF, sqb);
        }
    }
    out_kernel<<<1, 64, 0, stream>>>(sqb, rl, cl, ow1, ob1, ow2, ob2, out);
}